// Round 1
// baseline (2109.462 us; speedup 1.0000x reference)
//
#include <hip/hip_runtime.h>

#define FEAT 14
#define ROLE_DIM 16
#define IDX_DIM 8
#define IN_DIM 38       // 14 + 16 + 8
#define HID 128
#define IDX_VOCAB 1024
#define TILE 32

// ---------------------------------------------------------------------------
// Kernel A: x = [feat | role_emb[role] | idx_emb[i%1024]]; emb = relu(relu(x@W1+b1)@W2+b2)
// block = 256 threads, 32 nodes/block; thread (n = tid>>3, cg = tid&7) computes
// 16 output cols [cg*16, cg*16+16) for node n. x and h staged in LDS
// (per-k reads are 8-way broadcast); weights streamed as float4 (L1/L2-hot).
// ---------------------------------------------------------------------------
__global__ __launch_bounds__(256) void k_embed_mlp(
    const float* __restrict__ feat, const int* __restrict__ role_ids,
    const float* __restrict__ role_emb, const float* __restrict__ idx_emb,
    const float* __restrict__ W1, const float* __restrict__ b1,
    const float* __restrict__ W2, const float* __restrict__ b2,
    float* __restrict__ emb, int N)
{
    __shared__ float xs[TILE][IN_DIM];
    __shared__ float hs[TILE][HID];
    const int tid = threadIdx.x;
    const int node_base = blockIdx.x * TILE;

    // cooperative load of x tile
    for (int idx = tid; idx < TILE * IN_DIM; idx += 256) {
        int n = idx / IN_DIM;
        int k = idx - n * IN_DIM;
        int node = node_base + n;
        if (node >= N) node = N - 1;
        float v;
        if (k < FEAT)                 v = feat[node * FEAT + k];
        else if (k < FEAT + ROLE_DIM) v = role_emb[role_ids[node] * ROLE_DIM + (k - FEAT)];
        else                          v = idx_emb[(node % IDX_VOCAB) * IDX_DIM + (k - FEAT - ROLE_DIM)];
        xs[n][k] = v;
    }
    __syncthreads();

    const int n  = tid >> 3;
    const int cg = tid & 7;
    const int c0 = cg * 16;

    // phase 1: h = relu(x @ W1 + b1)
    float acc[16];
    {
        const float4* b4 = (const float4*)(b1 + c0);
        #pragma unroll
        for (int q = 0; q < 4; ++q) {
            float4 b = b4[q];
            acc[q*4+0] = b.x; acc[q*4+1] = b.y; acc[q*4+2] = b.z; acc[q*4+3] = b.w;
        }
    }
    #pragma unroll 2
    for (int k = 0; k < IN_DIM; ++k) {
        float xk = xs[n][k];
        const float4* wr = (const float4*)(W1 + k * HID + c0);
        #pragma unroll
        for (int q = 0; q < 4; ++q) {
            float4 w = wr[q];
            acc[q*4+0] = fmaf(xk, w.x, acc[q*4+0]);
            acc[q*4+1] = fmaf(xk, w.y, acc[q*4+1]);
            acc[q*4+2] = fmaf(xk, w.z, acc[q*4+2]);
            acc[q*4+3] = fmaf(xk, w.w, acc[q*4+3]);
        }
    }
    #pragma unroll
    for (int i = 0; i < 16; ++i) hs[n][c0 + i] = fmaxf(acc[i], 0.0f);
    __syncthreads();

    // phase 2: emb = relu(h @ W2 + b2)
    float acc2[16];
    {
        const float4* b4 = (const float4*)(b2 + c0);
        #pragma unroll
        for (int q = 0; q < 4; ++q) {
            float4 b = b4[q];
            acc2[q*4+0] = b.x; acc2[q*4+1] = b.y; acc2[q*4+2] = b.z; acc2[q*4+3] = b.w;
        }
    }
    #pragma unroll 2
    for (int k = 0; k < HID; ++k) {
        float hk = hs[n][k];
        const float4* wr = (const float4*)(W2 + k * HID + c0);
        #pragma unroll
        for (int q = 0; q < 4; ++q) {
            float4 w = wr[q];
            acc2[q*4+0] = fmaf(hk, w.x, acc2[q*4+0]);
            acc2[q*4+1] = fmaf(hk, w.y, acc2[q*4+1]);
            acc2[q*4+2] = fmaf(hk, w.z, acc2[q*4+2]);
            acc2[q*4+3] = fmaf(hk, w.w, acc2[q*4+3]);
        }
    }
    const int node = node_base + n;
    if (node < N) {
        float4* out = (float4*)(emb + (size_t)node * HID + c0);
        #pragma unroll
        for (int q = 0; q < 4; ++q) {
            float4 o;
            o.x = fmaxf(acc2[q*4+0], 0.0f);
            o.y = fmaxf(acc2[q*4+1], 0.0f);
            o.z = fmaxf(acc2[q*4+2], 0.0f);
            o.w = fmaxf(acc2[q*4+3], 0.0f);
            out[q] = o;
        }
    }
}

// ---------------------------------------------------------------------------
// Kernel B: pw[j] = sum of p2b_w where p2b_block == j (atomic histogram)
// ---------------------------------------------------------------------------
__global__ void k_pw(const int* __restrict__ pb, const float* __restrict__ pv,
                     float* __restrict__ pw, int P)
{
    int i = blockIdx.x * blockDim.x + threadIdx.x;
    int stride = gridDim.x * blockDim.x;
    for (; i < P; i += stride)
        atomicAdd(&pw[pb[i]], pv[i]);
}

// ---------------------------------------------------------------------------
// Kernel C: symmetric edge scatter. 128 threads per edge (1 float/thread),
// 2 edges per 256-thread block iteration, grid-stride.
// ---------------------------------------------------------------------------
__global__ __launch_bounds__(256) void k_edges(
    const int* __restrict__ src, const int* __restrict__ dst,
    const float* __restrict__ w, const float* __restrict__ emb,
    float* __restrict__ agg, int E)
{
    const int j = threadIdx.x & (HID - 1);
    int e = blockIdx.x * 2 + (threadIdx.x >> 7);
    const int stride = gridDim.x * 2;
    for (; e < E; e += stride) {
        int s = src[e];
        int d = dst[e];
        float wt = w[e];
        float es = emb[s * HID + j];
        float ed = emb[d * HID + j];
        atomicAdd(&agg[s * HID + j], ed * wt);
        atomicAdd(&agg[d * HID + j], es * wt);
    }
}

// ---------------------------------------------------------------------------
// Kernel D: a = agg + emb*pw; m = relu(a@M1+mb1)@M2+mb2; y = emb+m;
// out = LayerNorm(y)*g+b; block-partial graph sum -> atomicAdd(gsum).
// Same (n, cg) thread layout as kernel A.
// ---------------------------------------------------------------------------
__global__ __launch_bounds__(256) void k_msg_ln(
    const float* __restrict__ agg, const float* __restrict__ emb,
    const float* __restrict__ pw,
    const float* __restrict__ M1, const float* __restrict__ mb1,
    const float* __restrict__ M2, const float* __restrict__ mb2,
    const float* __restrict__ ln_g, const float* __restrict__ ln_b,
    float* __restrict__ out, float* __restrict__ gsum, int N)
{
    __shared__ float as[TILE][HID];
    __shared__ float hs[TILE][HID];
    __shared__ float wsum[4][HID];

    const int tid = threadIdx.x;
    const int n   = tid >> 3;
    const int cg  = tid & 7;
    const int c0  = cg * 16;
    const int node_base = blockIdx.x * TILE;
    const int node = node_base + n;
    const int nodec = node < N ? node : N - 1;

    // build a = agg + emb*pw tile; keep emb slice in registers for residual
    float ev[16];
    {
        float pwn = pw[nodec];
        const float4* e4p = (const float4*)(emb + (size_t)nodec * HID + c0);
        const float4* a4p = (const float4*)(agg + (size_t)nodec * HID + c0);
        #pragma unroll
        for (int q = 0; q < 4; ++q) {
            float4 e4 = e4p[q];
            float4 a4 = a4p[q];
            ev[q*4+0] = e4.x; ev[q*4+1] = e4.y; ev[q*4+2] = e4.z; ev[q*4+3] = e4.w;
            as[n][c0+q*4+0] = fmaf(e4.x, pwn, a4.x);
            as[n][c0+q*4+1] = fmaf(e4.y, pwn, a4.y);
            as[n][c0+q*4+2] = fmaf(e4.z, pwn, a4.z);
            as[n][c0+q*4+3] = fmaf(e4.w, pwn, a4.w);
        }
    }
    __syncthreads();

    // phase 1: hm = relu(a @ M1 + mb1)
    float acc[16];
    {
        const float4* b4 = (const float4*)(mb1 + c0);
        #pragma unroll
        for (int q = 0; q < 4; ++q) {
            float4 b = b4[q];
            acc[q*4+0] = b.x; acc[q*4+1] = b.y; acc[q*4+2] = b.z; acc[q*4+3] = b.w;
        }
    }
    #pragma unroll 2
    for (int k = 0; k < HID; ++k) {
        float ak = as[n][k];
        const float4* wr = (const float4*)(M1 + k * HID + c0);
        #pragma unroll
        for (int q = 0; q < 4; ++q) {
            float4 w = wr[q];
            acc[q*4+0] = fmaf(ak, w.x, acc[q*4+0]);
            acc[q*4+1] = fmaf(ak, w.y, acc[q*4+1]);
            acc[q*4+2] = fmaf(ak, w.z, acc[q*4+2]);
            acc[q*4+3] = fmaf(ak, w.w, acc[q*4+3]);
        }
    }
    #pragma unroll
    for (int i = 0; i < 16; ++i) hs[n][c0 + i] = fmaxf(acc[i], 0.0f);
    __syncthreads();

    // phase 2: y = emb + hm @ M2 + mb2
    float y[16];
    {
        const float4* b4 = (const float4*)(mb2 + c0);
        #pragma unroll
        for (int q = 0; q < 4; ++q) {
            float4 b = b4[q];
            y[q*4+0] = b.x; y[q*4+1] = b.y; y[q*4+2] = b.z; y[q*4+3] = b.w;
        }
    }
    #pragma unroll 2
    for (int k = 0; k < HID; ++k) {
        float hk = hs[n][k];
        const float4* wr = (const float4*)(M2 + k * HID + c0);
        #pragma unroll
        for (int q = 0; q < 4; ++q) {
            float4 w = wr[q];
            y[q*4+0] = fmaf(hk, w.x, y[q*4+0]);
            y[q*4+1] = fmaf(hk, w.y, y[q*4+1]);
            y[q*4+2] = fmaf(hk, w.z, y[q*4+2]);
            y[q*4+3] = fmaf(hk, w.w, y[q*4+3]);
        }
    }
    #pragma unroll
    for (int i = 0; i < 16; ++i) y[i] += ev[i];

    // LayerNorm across 128 channels = 8 threads (cg) x 16 values
    float s1 = 0.0f, s2 = 0.0f;
    #pragma unroll
    for (int i = 0; i < 16; ++i) { s1 += y[i]; s2 += y[i] * y[i]; }
    #pragma unroll
    for (int m = 1; m < 8; m <<= 1) {
        s1 += __shfl_xor(s1, m);
        s2 += __shfl_xor(s2, m);
    }
    float mu   = s1 * (1.0f / HID);
    float var  = s2 * (1.0f / HID) - mu * mu;
    float rstd = rsqrtf(var + 1e-5f);

    float o[16];
    #pragma unroll
    for (int i = 0; i < 16; ++i) {
        int c = c0 + i;
        o[i] = (y[i] - mu) * rstd * ln_g[c] + ln_b[c];
    }
    if (node < N) {
        float4* op = (float4*)(out + (size_t)node * HID + c0);
        #pragma unroll
        for (int q = 0; q < 4; ++q) {
            float4 v;
            v.x = o[q*4+0]; v.y = o[q*4+1]; v.z = o[q*4+2]; v.w = o[q*4+3];
            op[q] = v;
        }
    } else {
        #pragma unroll
        for (int i = 0; i < 16; ++i) o[i] = 0.0f;
    }

    // graph sum: reduce o over the 8 nodes within the wave (lane bits 3..5)
    #pragma unroll
    for (int m = 8; m < 64; m <<= 1) {
        #pragma unroll
        for (int i = 0; i < 16; ++i) o[i] += __shfl_xor(o[i], m);
    }
    const int lane = tid & 63;
    const int wv   = tid >> 6;
    if (lane < 8) {
        #pragma unroll
        for (int i = 0; i < 16; ++i) wsum[wv][lane * 16 + i] = o[i];
    }
    __syncthreads();
    if (tid < HID) {
        float s = wsum[0][tid] + wsum[1][tid] + wsum[2][tid] + wsum[3][tid];
        atomicAdd(&gsum[tid], s);
    }
}

// ---------------------------------------------------------------------------
// Kernel E: graph embedding = gsum / N
// ---------------------------------------------------------------------------
__global__ void k_graph(const float* __restrict__ gsum, float* __restrict__ out,
                        int N)
{
    int j = threadIdx.x;
    out[(size_t)N * HID + j] = gsum[j] * (1.0f / (float)N);
}

// ---------------------------------------------------------------------------
extern "C" void kernel_launch(void* const* d_in, const int* in_sizes, int n_in,
                              void* d_out, int out_size, void* d_ws, size_t ws_size,
                              hipStream_t stream)
{
    const float* feat      = (const float*)d_in[0];
    const int*   role_ids  = (const int*)  d_in[1];
    const int*   b2b_src   = (const int*)  d_in[2];
    const int*   b2b_dst   = (const int*)  d_in[3];
    const float* b2b_w     = (const float*)d_in[4];
    const int*   p2b_block = (const int*)  d_in[5];
    const float* p2b_w     = (const float*)d_in[6];
    const float* role_emb  = (const float*)d_in[7];
    const float* idx_emb   = (const float*)d_in[8];
    const float* W1        = (const float*)d_in[9];
    const float* b1        = (const float*)d_in[10];
    const float* W2        = (const float*)d_in[11];
    const float* b2        = (const float*)d_in[12];
    const float* M1        = (const float*)d_in[13];
    const float* mb1       = (const float*)d_in[14];
    const float* M2        = (const float*)d_in[15];
    const float* mb2       = (const float*)d_in[16];
    const float* ln_g      = (const float*)d_in[17];
    const float* ln_b      = (const float*)d_in[18];

    const int N = in_sizes[1];
    const int E = in_sizes[2];
    const int P = in_sizes[5];

    float* out = (float*)d_out;

    // workspace layout
    char* ws = (char*)d_ws;
    size_t embBytes = (size_t)N * HID * sizeof(float);
    size_t aggBytes = (size_t)N * HID * sizeof(float);
    size_t pwBytes  = (size_t)N * sizeof(float);
    float* emb  = (float*)ws;
    float* agg  = (float*)(ws + embBytes);
    float* pw   = (float*)(ws + embBytes + aggBytes);
    float* gsum = (float*)(ws + embBytes + aggBytes + pwBytes);

    // zero agg | pw | gsum (contiguous)
    hipMemsetAsync(agg, 0, aggBytes + pwBytes + HID * sizeof(float), stream);

    const int nBlocksTile = (N + TILE - 1) / TILE;

    k_embed_mlp<<<nBlocksTile, 256, 0, stream>>>(
        feat, role_ids, role_emb, idx_emb, W1, b1, W2, b2, emb, N);

    k_pw<<<4096, 256, 0, stream>>>(p2b_block, p2b_w, pw, P);

    k_edges<<<8192, 256, 0, stream>>>(b2b_src, b2b_dst, b2b_w, emb, agg, E);

    k_msg_ln<<<nBlocksTile, 256, 0, stream>>>(
        agg, emb, pw, M1, mb1, M2, mb2, ln_g, ln_b, out, gsum, N);

    k_graph<<<1, HID, 0, stream>>>(gsum, out, N);
}

// Round 2
// 1860.673 us; speedup vs baseline: 1.1337x; 1.1337x over previous
//
#include <hip/hip_runtime.h>

#define FEAT 14
#define ROLE_DIM 16
#define IDX_DIM 8
#define IN_DIM 38       // 14 + 16 + 8
#define HID 128
#define HIDP (HID + 4)  // LDS pad: bank = (4n+k)%32 -> conflict-free over 8 node-groups
#define IDX_VOCAB 1024
#define TILE 32

// ---------------------------------------------------------------------------
// Kernel A: x = [feat | role_emb[role] | idx_emb[i%1024]]; emb = relu(relu(x@W1+b1)@W2+b2)
// 256 threads, 32 nodes/block; thread (n = tid>>3, cg = tid&7) computes 16 cols.
// ---------------------------------------------------------------------------
__global__ __launch_bounds__(256) void k_embed_mlp(
    const float* __restrict__ feat, const int* __restrict__ role_ids,
    const float* __restrict__ role_emb, const float* __restrict__ idx_emb,
    const float* __restrict__ W1, const float* __restrict__ b1,
    const float* __restrict__ W2, const float* __restrict__ b2,
    float* __restrict__ emb, int N)
{
    __shared__ float xs[TILE][IN_DIM];   // stride 38: bank (6n+k)%32, conflict-free
    __shared__ float hs[TILE][HIDP];
    const int tid = threadIdx.x;
    const int node_base = blockIdx.x * TILE;

    for (int idx = tid; idx < TILE * IN_DIM; idx += 256) {
        int n = idx / IN_DIM;
        int k = idx - n * IN_DIM;
        int node = node_base + n;
        if (node >= N) node = N - 1;
        float v;
        if (k < FEAT)                 v = feat[node * FEAT + k];
        else if (k < FEAT + ROLE_DIM) v = role_emb[role_ids[node] * ROLE_DIM + (k - FEAT)];
        else                          v = idx_emb[(node % IDX_VOCAB) * IDX_DIM + (k - FEAT - ROLE_DIM)];
        xs[n][k] = v;
    }
    __syncthreads();

    const int n  = tid >> 3;
    const int cg = tid & 7;
    const int c0 = cg * 16;

    // phase 1: h = relu(x @ W1 + b1)
    float acc[16];
    {
        const float4* b4 = (const float4*)(b1 + c0);
        #pragma unroll
        for (int q = 0; q < 4; ++q) {
            float4 b = b4[q];
            acc[q*4+0] = b.x; acc[q*4+1] = b.y; acc[q*4+2] = b.z; acc[q*4+3] = b.w;
        }
    }
    #pragma unroll 2
    for (int k = 0; k < IN_DIM; ++k) {
        float xk = xs[n][k];
        const float4* wr = (const float4*)(W1 + k * HID + c0);
        #pragma unroll
        for (int q = 0; q < 4; ++q) {
            float4 w = wr[q];
            acc[q*4+0] = fmaf(xk, w.x, acc[q*4+0]);
            acc[q*4+1] = fmaf(xk, w.y, acc[q*4+1]);
            acc[q*4+2] = fmaf(xk, w.z, acc[q*4+2]);
            acc[q*4+3] = fmaf(xk, w.w, acc[q*4+3]);
        }
    }
    #pragma unroll
    for (int i = 0; i < 16; ++i) hs[n][c0 + i] = fmaxf(acc[i], 0.0f);
    __syncthreads();

    // phase 2: emb = relu(h @ W2 + b2)
    float acc2[16];
    {
        const float4* b4 = (const float4*)(b2 + c0);
        #pragma unroll
        for (int q = 0; q < 4; ++q) {
            float4 b = b4[q];
            acc2[q*4+0] = b.x; acc2[q*4+1] = b.y; acc2[q*4+2] = b.z; acc2[q*4+3] = b.w;
        }
    }
    #pragma unroll 2
    for (int k = 0; k < HID; ++k) {
        float hk = hs[n][k];
        const float4* wr = (const float4*)(W2 + k * HID + c0);
        #pragma unroll
        for (int q = 0; q < 4; ++q) {
            float4 w = wr[q];
            acc2[q*4+0] = fmaf(hk, w.x, acc2[q*4+0]);
            acc2[q*4+1] = fmaf(hk, w.y, acc2[q*4+1]);
            acc2[q*4+2] = fmaf(hk, w.z, acc2[q*4+2]);
            acc2[q*4+3] = fmaf(hk, w.w, acc2[q*4+3]);
        }
    }
    const int node = node_base + n;
    if (node < N) {
        float4* out = (float4*)(emb + (size_t)node * HID + c0);
        #pragma unroll
        for (int q = 0; q < 4; ++q) {
            float4 o;
            o.x = fmaxf(acc2[q*4+0], 0.0f);
            o.y = fmaxf(acc2[q*4+1], 0.0f);
            o.z = fmaxf(acc2[q*4+2], 0.0f);
            o.w = fmaxf(acc2[q*4+3], 0.0f);
            out[q] = o;
        }
    }
}

// ---------------------------------------------------------------------------
// Kernel B: pw[j] = sum of p2b_w where p2b_block == j
// ---------------------------------------------------------------------------
__global__ void k_pw(const int* __restrict__ pb, const float* __restrict__ pv,
                     float* __restrict__ pw, int P)
{
    int i = blockIdx.x * blockDim.x + threadIdx.x;
    int stride = gridDim.x * blockDim.x;
    for (; i < P; i += stride)
        atomicAdd(&pw[pb[i]], pv[i]);
}

// ---------------------------------------------------------------------------
// CSR build: count -> scan -> scatter
// ---------------------------------------------------------------------------
__global__ void k_count(const int* __restrict__ src, const int* __restrict__ dst,
                        int* __restrict__ count, int E)
{
    int i = blockIdx.x * blockDim.x + threadIdx.x;
    int stride = gridDim.x * blockDim.x;
    for (; i < E; i += stride) {
        atomicAdd(&count[src[i]], 1);
        atomicAdd(&count[dst[i]], 1);
    }
}

// single-block exclusive scan over N counts; writes start[] and cursor[]
__global__ __launch_bounds__(1024) void k_scan(const int* __restrict__ count,
    int* __restrict__ start, int* __restrict__ cursor, int N)
{
    __shared__ int tsum[1024];
    const int tid = threadIdx.x;
    const int per = (N + 1023) / 1024;
    const int lo = tid * per;
    const int hi = (lo + per) < N ? (lo + per) : N;
    int s = 0;
    for (int i = lo; i < hi; ++i) s += count[i];
    tsum[tid] = s;
    __syncthreads();
    for (int off = 1; off < 1024; off <<= 1) {
        int v = (tid >= off) ? tsum[tid - off] : 0;
        __syncthreads();
        tsum[tid] += v;
        __syncthreads();
    }
    int run = (tid == 0) ? 0 : tsum[tid - 1];
    for (int i = lo; i < hi; ++i) {
        start[i] = run;
        cursor[i] = run;
        run += count[i];
    }
}

__global__ void k_scatter(const int* __restrict__ src, const int* __restrict__ dst,
                          const float* __restrict__ w, int* __restrict__ cursor,
                          int2* __restrict__ entries, int E)
{
    int i = blockIdx.x * blockDim.x + threadIdx.x;
    int stride = gridDim.x * blockDim.x;
    for (; i < E; i += stride) {
        int s = src[i];
        int d = dst[i];
        int wi = __float_as_int(w[i]);
        int p = atomicAdd(&cursor[s], 1);
        entries[p] = make_int2(d, wi);
        int q = atomicAdd(&cursor[d], 1);
        entries[q] = make_int2(s, wi);
    }
}

// ---------------------------------------------------------------------------
// Kernel D (fused): agg = sum_nb emb[nb]*w + emb*pw (in registers, no atomics);
// m = relu(agg@M1+mb1)@M2+mb2; out = LN(emb+m); graph partial sum -> gsum.
// ---------------------------------------------------------------------------
__global__ __launch_bounds__(256) void k_msg_ln(
    const float* __restrict__ emb, const int2* __restrict__ entries,
    const int* __restrict__ start, const int* __restrict__ count,
    const float* __restrict__ pw,
    const float* __restrict__ M1, const float* __restrict__ mb1,
    const float* __restrict__ M2, const float* __restrict__ mb2,
    const float* __restrict__ ln_g, const float* __restrict__ ln_b,
    float* __restrict__ out, float* __restrict__ gsum, int N)
{
    __shared__ float as[TILE][HIDP];
    __shared__ float hs[TILE][HIDP];
    __shared__ float wsum[4][HID];

    const int tid = threadIdx.x;
    const int n   = tid >> 3;
    const int cg  = tid & 7;
    const int c0  = cg * 16;
    const int node_base = blockIdx.x * TILE;
    const int node = node_base + n;
    const int nodec = node < N ? node : N - 1;
    const bool valid = node < N;

    // init acc = emb*pw; keep emb slice for residual
    float ev[16], acc[16];
    {
        float pwn = valid ? pw[nodec] : 0.0f;
        const float4* e4p = (const float4*)(emb + (size_t)nodec * HID + c0);
        #pragma unroll
        for (int q = 0; q < 4; ++q) {
            float4 e4 = e4p[q];
            ev[q*4+0] = e4.x; ev[q*4+1] = e4.y; ev[q*4+2] = e4.z; ev[q*4+3] = e4.w;
            acc[q*4+0] = e4.x * pwn; acc[q*4+1] = e4.y * pwn;
            acc[q*4+2] = e4.z * pwn; acc[q*4+3] = e4.w * pwn;
        }
    }

    // gather neighbors (CSR), accumulate in registers — no atomics
    {
        int st  = valid ? start[nodec] : 0;
        int deg = valid ? count[nodec] : 0;
        #pragma unroll 2
        for (int i = 0; i < deg; ++i) {
            int2 en = entries[st + i];
            float wt = __int_as_float(en.y);
            const float4* nb4 = (const float4*)(emb + (size_t)en.x * HID + c0);
            #pragma unroll
            for (int q = 0; q < 4; ++q) {
                float4 f = nb4[q];
                acc[q*4+0] = fmaf(f.x, wt, acc[q*4+0]);
                acc[q*4+1] = fmaf(f.y, wt, acc[q*4+1]);
                acc[q*4+2] = fmaf(f.z, wt, acc[q*4+2]);
                acc[q*4+3] = fmaf(f.w, wt, acc[q*4+3]);
            }
        }
    }
    #pragma unroll
    for (int i = 0; i < 16; ++i) as[n][c0 + i] = acc[i];
    __syncthreads();

    // phase 1: hm = relu(a @ M1 + mb1)
    float a1[16];
    {
        const float4* b4 = (const float4*)(mb1 + c0);
        #pragma unroll
        for (int q = 0; q < 4; ++q) {
            float4 b = b4[q];
            a1[q*4+0] = b.x; a1[q*4+1] = b.y; a1[q*4+2] = b.z; a1[q*4+3] = b.w;
        }
    }
    #pragma unroll 2
    for (int k = 0; k < HID; ++k) {
        float ak = as[n][k];
        const float4* wr = (const float4*)(M1 + k * HID + c0);
        #pragma unroll
        for (int q = 0; q < 4; ++q) {
            float4 w = wr[q];
            a1[q*4+0] = fmaf(ak, w.x, a1[q*4+0]);
            a1[q*4+1] = fmaf(ak, w.y, a1[q*4+1]);
            a1[q*4+2] = fmaf(ak, w.z, a1[q*4+2]);
            a1[q*4+3] = fmaf(ak, w.w, a1[q*4+3]);
        }
    }
    #pragma unroll
    for (int i = 0; i < 16; ++i) hs[n][c0 + i] = fmaxf(a1[i], 0.0f);
    __syncthreads();

    // phase 2: y = emb + hm @ M2 + mb2
    float y[16];
    {
        const float4* b4 = (const float4*)(mb2 + c0);
        #pragma unroll
        for (int q = 0; q < 4; ++q) {
            float4 b = b4[q];
            y[q*4+0] = b.x; y[q*4+1] = b.y; y[q*4+2] = b.z; y[q*4+3] = b.w;
        }
    }
    #pragma unroll 2
    for (int k = 0; k < HID; ++k) {
        float hk = hs[n][k];
        const float4* wr = (const float4*)(M2 + k * HID + c0);
        #pragma unroll
        for (int q = 0; q < 4; ++q) {
            float4 w = wr[q];
            y[q*4+0] = fmaf(hk, w.x, y[q*4+0]);
            y[q*4+1] = fmaf(hk, w.y, y[q*4+1]);
            y[q*4+2] = fmaf(hk, w.z, y[q*4+2]);
            y[q*4+3] = fmaf(hk, w.w, y[q*4+3]);
        }
    }
    #pragma unroll
    for (int i = 0; i < 16; ++i) y[i] += ev[i];

    // LayerNorm across 8 threads (cg) x 16
    float s1 = 0.0f, s2 = 0.0f;
    #pragma unroll
    for (int i = 0; i < 16; ++i) { s1 += y[i]; s2 += y[i] * y[i]; }
    #pragma unroll
    for (int m = 1; m < 8; m <<= 1) {
        s1 += __shfl_xor(s1, m);
        s2 += __shfl_xor(s2, m);
    }
    float mu   = s1 * (1.0f / HID);
    float var  = s2 * (1.0f / HID) - mu * mu;
    float rstd = rsqrtf(var + 1e-5f);

    float o[16];
    #pragma unroll
    for (int i = 0; i < 16; ++i) {
        int c = c0 + i;
        o[i] = (y[i] - mu) * rstd * ln_g[c] + ln_b[c];
    }
    if (valid) {
        float4* op = (float4*)(out + (size_t)node * HID + c0);
        #pragma unroll
        for (int q = 0; q < 4; ++q) {
            float4 v;
            v.x = o[q*4+0]; v.y = o[q*4+1]; v.z = o[q*4+2]; v.w = o[q*4+3];
            op[q] = v;
        }
    } else {
        #pragma unroll
        for (int i = 0; i < 16; ++i) o[i] = 0.0f;
    }

    // graph sum: reduce over the 8 nodes within the wave
    #pragma unroll
    for (int m = 8; m < 64; m <<= 1) {
        #pragma unroll
        for (int i = 0; i < 16; ++i) o[i] += __shfl_xor(o[i], m);
    }
    const int lane = tid & 63;
    const int wv   = tid >> 6;
    if (lane < 8) {
        #pragma unroll
        for (int i = 0; i < 16; ++i) wsum[wv][lane * 16 + i] = o[i];
    }
    __syncthreads();
    if (tid < HID) {
        float s = wsum[0][tid] + wsum[1][tid] + wsum[2][tid] + wsum[3][tid];
        atomicAdd(&gsum[tid], s);
    }
}

// ---------------------------------------------------------------------------
__global__ void k_graph(const float* __restrict__ gsum, float* __restrict__ out,
                        int N)
{
    int j = threadIdx.x;
    out[(size_t)N * HID + j] = gsum[j] * (1.0f / (float)N);
}

// ---------------------------------------------------------------------------
extern "C" void kernel_launch(void* const* d_in, const int* in_sizes, int n_in,
                              void* d_out, int out_size, void* d_ws, size_t ws_size,
                              hipStream_t stream)
{
    const float* feat      = (const float*)d_in[0];
    const int*   role_ids  = (const int*)  d_in[1];
    const int*   b2b_src   = (const int*)  d_in[2];
    const int*   b2b_dst   = (const int*)  d_in[3];
    const float* b2b_w     = (const float*)d_in[4];
    const int*   p2b_block = (const int*)  d_in[5];
    const float* p2b_w     = (const float*)d_in[6];
    const float* role_emb  = (const float*)d_in[7];
    const float* idx_emb   = (const float*)d_in[8];
    const float* W1        = (const float*)d_in[9];
    const float* b1        = (const float*)d_in[10];
    const float* W2        = (const float*)d_in[11];
    const float* b2        = (const float*)d_in[12];
    const float* M1        = (const float*)d_in[13];
    const float* mb1       = (const float*)d_in[14];
    const float* M2        = (const float*)d_in[15];
    const float* mb2       = (const float*)d_in[16];
    const float* ln_g      = (const float*)d_in[17];
    const float* ln_b      = (const float*)d_in[18];

    const int N = in_sizes[1];
    const int E = in_sizes[2];
    const int P = in_sizes[5];

    float* out = (float*)d_out;

    // workspace layout (all 16B-aligned)
    char* ws = (char*)d_ws;
    size_t embBytes  = (size_t)N * HID * sizeof(float);   // 51.2 MB
    size_t entBytes  = (size_t)2 * E * sizeof(int2);      // 16 MB
    size_t vecBytes  = (size_t)N * sizeof(int);           // 400 KB each

    float* emb     = (float*)ws;                         ws += embBytes;
    int2*  entries = (int2*)ws;                          ws += entBytes;
    int*   startA  = (int*)ws;                           ws += vecBytes;
    int*   cursor  = (int*)ws;                           ws += vecBytes;
    int*   count   = (int*)ws;                           ws += vecBytes;
    float* pw      = (float*)ws;                         ws += vecBytes;
    float* gsum    = (float*)ws;                         ws += HID * sizeof(float);

    // zero count | pw | gsum (contiguous)
    hipMemsetAsync(count, 0, 2 * vecBytes + HID * sizeof(float), stream);

    const int nBlocksTile = (N + TILE - 1) / TILE;

    k_embed_mlp<<<nBlocksTile, 256, 0, stream>>>(
        feat, role_ids, role_emb, idx_emb, W1, b1, W2, b2, emb, N);

    k_count<<<2048, 256, 0, stream>>>(b2b_src, b2b_dst, count, E);

    k_pw<<<2048, 256, 0, stream>>>(p2b_block, p2b_w, pw, P);

    k_scan<<<1, 1024, 0, stream>>>(count, startA, cursor, N);

    k_scatter<<<2048, 256, 0, stream>>>(b2b_src, b2b_dst, b2b_w, cursor, entries, E);

    k_msg_ln<<<nBlocksTile, 256, 0, stream>>>(
        emb, entries, startA, count, pw, M1, mb1, M2, mb2, ln_g, ln_b,
        out, gsum, N);

    k_graph<<<1, HID, 0, stream>>>(gsum, out, N);
}

// Round 3
// 1859.882 us; speedup vs baseline: 1.1342x; 1.0004x over previous
//
#include <hip/hip_runtime.h>

#define FEAT 14
#define ROLE_DIM 16
#define IDX_DIM 8
#define IN_DIM 38       // 14 + 16 + 8
#define HID 128
#define HIDP (HID + 4)
#define IDX_VOCAB 1024
#define TILE 32

// bf16 round-to-nearest-even pack
__device__ __forceinline__ ushort f2bf(float f) {
    uint u = __float_as_uint(f);
    return (ushort)((u + 0x7FFFu + ((u >> 16) & 1u)) >> 16);
}

// ---------------------------------------------------------------------------
// Kernel A: emb = relu(relu(x@W1+b1)@W2+b2); also writes bf16 replica embh.
// ---------------------------------------------------------------------------
__global__ __launch_bounds__(256) void k_embed_mlp(
    const float* __restrict__ feat, const int* __restrict__ role_ids,
    const float* __restrict__ role_emb, const float* __restrict__ idx_emb,
    const float* __restrict__ W1, const float* __restrict__ b1,
    const float* __restrict__ W2, const float* __restrict__ b2,
    float* __restrict__ emb, ushort* __restrict__ embh, int N)
{
    __shared__ float xs[TILE][IN_DIM];
    __shared__ float hs[TILE][HIDP];
    const int tid = threadIdx.x;
    const int node_base = blockIdx.x * TILE;

    for (int idx = tid; idx < TILE * IN_DIM; idx += 256) {
        int n = idx / IN_DIM;
        int k = idx - n * IN_DIM;
        int node = node_base + n;
        if (node >= N) node = N - 1;
        float v;
        if (k < FEAT)                 v = feat[node * FEAT + k];
        else if (k < FEAT + ROLE_DIM) v = role_emb[role_ids[node] * ROLE_DIM + (k - FEAT)];
        else                          v = idx_emb[(node % IDX_VOCAB) * IDX_DIM + (k - FEAT - ROLE_DIM)];
        xs[n][k] = v;
    }
    __syncthreads();

    const int n  = tid >> 3;
    const int cg = tid & 7;
    const int c0 = cg * 16;

    float acc[16];
    {
        const float4* b4 = (const float4*)(b1 + c0);
        #pragma unroll
        for (int q = 0; q < 4; ++q) {
            float4 b = b4[q];
            acc[q*4+0] = b.x; acc[q*4+1] = b.y; acc[q*4+2] = b.z; acc[q*4+3] = b.w;
        }
    }
    #pragma unroll 2
    for (int k = 0; k < IN_DIM; ++k) {
        float xk = xs[n][k];
        const float4* wr = (const float4*)(W1 + k * HID + c0);
        #pragma unroll
        for (int q = 0; q < 4; ++q) {
            float4 w = wr[q];
            acc[q*4+0] = fmaf(xk, w.x, acc[q*4+0]);
            acc[q*4+1] = fmaf(xk, w.y, acc[q*4+1]);
            acc[q*4+2] = fmaf(xk, w.z, acc[q*4+2]);
            acc[q*4+3] = fmaf(xk, w.w, acc[q*4+3]);
        }
    }
    #pragma unroll
    for (int i = 0; i < 16; ++i) hs[n][c0 + i] = fmaxf(acc[i], 0.0f);
    __syncthreads();

    float acc2[16];
    {
        const float4* b4 = (const float4*)(b2 + c0);
        #pragma unroll
        for (int q = 0; q < 4; ++q) {
            float4 b = b4[q];
            acc2[q*4+0] = b.x; acc2[q*4+1] = b.y; acc2[q*4+2] = b.z; acc2[q*4+3] = b.w;
        }
    }
    #pragma unroll 2
    for (int k = 0; k < HID; ++k) {
        float hk = hs[n][k];
        const float4* wr = (const float4*)(W2 + k * HID + c0);
        #pragma unroll
        for (int q = 0; q < 4; ++q) {
            float4 w = wr[q];
            acc2[q*4+0] = fmaf(hk, w.x, acc2[q*4+0]);
            acc2[q*4+1] = fmaf(hk, w.y, acc2[q*4+1]);
            acc2[q*4+2] = fmaf(hk, w.z, acc2[q*4+2]);
            acc2[q*4+3] = fmaf(hk, w.w, acc2[q*4+3]);
        }
    }
    const int node = node_base + n;
    if (node < N) {
        float o[16];
        #pragma unroll
        for (int i = 0; i < 16; ++i) o[i] = fmaxf(acc2[i], 0.0f);
        float4* op = (float4*)(emb + (size_t)node * HID + c0);
        #pragma unroll
        for (int q = 0; q < 4; ++q) {
            float4 v;
            v.x = o[q*4+0]; v.y = o[q*4+1]; v.z = o[q*4+2]; v.w = o[q*4+3];
            op[q] = v;
        }
        // bf16 replica for the gather
        uint p[8];
        #pragma unroll
        for (int j = 0; j < 8; ++j)
            p[j] = (uint)f2bf(o[2*j]) | ((uint)f2bf(o[2*j+1]) << 16);
        uint4* hp = (uint4*)(embh + ((size_t)node << 7) + c0);
        hp[0] = make_uint4(p[0], p[1], p[2], p[3]);
        hp[1] = make_uint4(p[4], p[5], p[6], p[7]);
    }
}

// ---------------------------------------------------------------------------
// Kernel B: degree count (both directions) + pin-weight histogram, fused.
// ---------------------------------------------------------------------------
__global__ void k_count_pw(const int* __restrict__ src, const int* __restrict__ dst,
                           int* __restrict__ count,
                           const int* __restrict__ pb, const float* __restrict__ pv,
                           float* __restrict__ pw, int E, int P)
{
    int i = blockIdx.x * blockDim.x + threadIdx.x;
    int stride = gridDim.x * blockDim.x;
    int M = E > P ? E : P;
    for (; i < M; i += stride) {
        if (i < E) {
            atomicAdd(&count[src[i]], 1);
            atomicAdd(&count[dst[i]], 1);
        }
        if (i < P)
            atomicAdd(&pw[pb[i]], pv[i]);
    }
}

// single-block exclusive scan over N counts; writes start[] and cursor[]
__global__ __launch_bounds__(1024) void k_scan(const int* __restrict__ count,
    int* __restrict__ start, int* __restrict__ cursor, int N)
{
    __shared__ int tsum[1024];
    const int tid = threadIdx.x;
    const int per = (N + 1023) / 1024;
    const int lo = tid * per;
    const int hi = (lo + per) < N ? (lo + per) : N;
    int s = 0;
    for (int i = lo; i < hi; ++i) s += count[i];
    tsum[tid] = s;
    __syncthreads();
    for (int off = 1; off < 1024; off <<= 1) {
        int v = (tid >= off) ? tsum[tid - off] : 0;
        __syncthreads();
        tsum[tid] += v;
        __syncthreads();
    }
    int run = (tid == 0) ? 0 : tsum[tid - 1];
    for (int i = lo; i < hi; ++i) {
        start[i] = run;
        cursor[i] = run;
        run += count[i];
    }
}

// entries packed: (nbr << 15) | round(w * 32767)
__global__ void k_scatter(const int* __restrict__ src, const int* __restrict__ dst,
                          const float* __restrict__ w, int* __restrict__ cursor,
                          uint* __restrict__ entries, int E)
{
    int i = blockIdx.x * blockDim.x + threadIdx.x;
    int stride = gridDim.x * blockDim.x;
    for (; i < E; i += stride) {
        int s = src[i];
        int d = dst[i];
        uint q = (uint)(w[i] * 32767.0f + 0.5f);
        int p0 = atomicAdd(&cursor[s], 1);
        entries[p0] = ((uint)d << 15) | q;
        int p1 = atomicAdd(&cursor[d], 1);
        entries[p1] = ((uint)s << 15) | q;
    }
}

// ---------------------------------------------------------------------------
// Kernel C: zero-LDS register gather: agg = emb*pw + sum_nb bf16(emb[nb])*w.
// 8 threads/node, 16 cols each; full occupancy for latency hiding.
// ---------------------------------------------------------------------------
__global__ __launch_bounds__(256) void k_gather(
    const ushort* __restrict__ embh, const float* __restrict__ emb,
    const uint* __restrict__ entries, const int* __restrict__ start,
    const int* __restrict__ count, const float* __restrict__ pw,
    float* __restrict__ agg, int N)
{
    const int tid = threadIdx.x;
    const int node = blockIdx.x * TILE + (tid >> 3);
    const int cg = tid & 7;
    const int c0 = cg * 16;
    if (node >= N) return;

    float acc[16];
    {
        float pwn = pw[node];
        const float4* e4p = (const float4*)(emb + (size_t)node * HID + c0);
        #pragma unroll
        for (int q = 0; q < 4; ++q) {
            float4 e4 = e4p[q];
            acc[q*4+0] = e4.x * pwn; acc[q*4+1] = e4.y * pwn;
            acc[q*4+2] = e4.z * pwn; acc[q*4+3] = e4.w * pwn;
        }
    }

    const int st  = start[node];
    const int deg = count[node];
    const uint* ep = entries + st;
    #pragma unroll 4
    for (int i = 0; i < deg; ++i) {
        uint en = ep[i];
        int nb   = (int)(en >> 15);
        float wt = (float)(en & 32767u) * (1.0f / 32767.0f);
        const uint4* r = (const uint4*)(embh + ((size_t)nb << 7) + c0);
        uint4 u0 = r[0];
        uint4 u1 = r[1];
        uint uu[8] = {u0.x, u0.y, u0.z, u0.w, u1.x, u1.y, u1.z, u1.w};
        #pragma unroll
        for (int j = 0; j < 8; ++j) {
            float lo = __uint_as_float(uu[j] << 16);
            float hi = __uint_as_float(uu[j] & 0xffff0000u);
            acc[2*j]   = fmaf(lo, wt, acc[2*j]);
            acc[2*j+1] = fmaf(hi, wt, acc[2*j+1]);
        }
    }

    float4* ap = (float4*)(agg + (size_t)node * HID + c0);
    #pragma unroll
    for (int q = 0; q < 4; ++q)
        ap[q] = make_float4(acc[q*4+0], acc[q*4+1], acc[q*4+2], acc[q*4+3]);
}

// ---------------------------------------------------------------------------
// Kernel D: m = relu(agg@M1+mb1)@M2+mb2; out = LN(emb+m); partial gsum.
// ---------------------------------------------------------------------------
__global__ __launch_bounds__(256) void k_msg_ln(
    const float* __restrict__ agg, const float* __restrict__ emb,
    const float* __restrict__ M1, const float* __restrict__ mb1,
    const float* __restrict__ M2, const float* __restrict__ mb2,
    const float* __restrict__ ln_g, const float* __restrict__ ln_b,
    float* __restrict__ out, float* __restrict__ gsum, int N)
{
    __shared__ float as[TILE][HIDP];
    __shared__ float hs[TILE][HIDP];
    __shared__ float wsum[4][HID];

    const int tid = threadIdx.x;
    const int n   = tid >> 3;
    const int cg  = tid & 7;
    const int c0  = cg * 16;
    const int node_base = blockIdx.x * TILE;
    const int node = node_base + n;
    const int nodec = node < N ? node : N - 1;
    const bool valid = node < N;

    float ev[16];
    {
        const float4* e4p = (const float4*)(emb + (size_t)nodec * HID + c0);
        const float4* a4p = (const float4*)(agg + (size_t)nodec * HID + c0);
        #pragma unroll
        for (int q = 0; q < 4; ++q) {
            float4 e4 = e4p[q];
            float4 a4 = a4p[q];
            ev[q*4+0] = e4.x; ev[q*4+1] = e4.y; ev[q*4+2] = e4.z; ev[q*4+3] = e4.w;
            as[n][c0+q*4+0] = a4.x; as[n][c0+q*4+1] = a4.y;
            as[n][c0+q*4+2] = a4.z; as[n][c0+q*4+3] = a4.w;
        }
    }
    __syncthreads();

    float a1[16];
    {
        const float4* b4 = (const float4*)(mb1 + c0);
        #pragma unroll
        for (int q = 0; q < 4; ++q) {
            float4 b = b4[q];
            a1[q*4+0] = b.x; a1[q*4+1] = b.y; a1[q*4+2] = b.z; a1[q*4+3] = b.w;
        }
    }
    #pragma unroll 2
    for (int k = 0; k < HID; ++k) {
        float ak = as[n][k];
        const float4* wr = (const float4*)(M1 + k * HID + c0);
        #pragma unroll
        for (int q = 0; q < 4; ++q) {
            float4 w = wr[q];
            a1[q*4+0] = fmaf(ak, w.x, a1[q*4+0]);
            a1[q*4+1] = fmaf(ak, w.y, a1[q*4+1]);
            a1[q*4+2] = fmaf(ak, w.z, a1[q*4+2]);
            a1[q*4+3] = fmaf(ak, w.w, a1[q*4+3]);
        }
    }
    #pragma unroll
    for (int i = 0; i < 16; ++i) hs[n][c0 + i] = fmaxf(a1[i], 0.0f);
    __syncthreads();

    float y[16];
    {
        const float4* b4 = (const float4*)(mb2 + c0);
        #pragma unroll
        for (int q = 0; q < 4; ++q) {
            float4 b = b4[q];
            y[q*4+0] = b.x; y[q*4+1] = b.y; y[q*4+2] = b.z; y[q*4+3] = b.w;
        }
    }
    #pragma unroll 2
    for (int k = 0; k < HID; ++k) {
        float hk = hs[n][k];
        const float4* wr = (const float4*)(M2 + k * HID + c0);
        #pragma unroll
        for (int q = 0; q < 4; ++q) {
            float4 w = wr[q];
            y[q*4+0] = fmaf(hk, w.x, y[q*4+0]);
            y[q*4+1] = fmaf(hk, w.y, y[q*4+1]);
            y[q*4+2] = fmaf(hk, w.z, y[q*4+2]);
            y[q*4+3] = fmaf(hk, w.w, y[q*4+3]);
        }
    }
    #pragma unroll
    for (int i = 0; i < 16; ++i) y[i] += ev[i];

    float s1 = 0.0f, s2 = 0.0f;
    #pragma unroll
    for (int i = 0; i < 16; ++i) { s1 += y[i]; s2 += y[i] * y[i]; }
    #pragma unroll
    for (int m = 1; m < 8; m <<= 1) {
        s1 += __shfl_xor(s1, m);
        s2 += __shfl_xor(s2, m);
    }
    float mu   = s1 * (1.0f / HID);
    float var  = s2 * (1.0f / HID) - mu * mu;
    float rstd = rsqrtf(var + 1e-5f);

    float o[16];
    #pragma unroll
    for (int i = 0; i < 16; ++i) {
        int c = c0 + i;
        o[i] = (y[i] - mu) * rstd * ln_g[c] + ln_b[c];
    }
    if (valid) {
        float4* op = (float4*)(out + (size_t)node * HID + c0);
        #pragma unroll
        for (int q = 0; q < 4; ++q) {
            float4 v;
            v.x = o[q*4+0]; v.y = o[q*4+1]; v.z = o[q*4+2]; v.w = o[q*4+3];
            op[q] = v;
        }
    } else {
        #pragma unroll
        for (int i = 0; i < 16; ++i) o[i] = 0.0f;
    }

    #pragma unroll
    for (int m = 8; m < 64; m <<= 1) {
        #pragma unroll
        for (int i = 0; i < 16; ++i) o[i] += __shfl_xor(o[i], m);
    }
    const int lane = tid & 63;
    const int wv   = tid >> 6;
    if (lane < 8) {
        #pragma unroll
        for (int i = 0; i < 16; ++i) wsum[wv][lane * 16 + i] = o[i];
    }
    __syncthreads();
    if (tid < HID) {
        float s = wsum[0][tid] + wsum[1][tid] + wsum[2][tid] + wsum[3][tid];
        atomicAdd(&gsum[tid], s);
    }
}

// ---------------------------------------------------------------------------
__global__ void k_graph(const float* __restrict__ gsum, float* __restrict__ out,
                        int N)
{
    int j = threadIdx.x;
    out[(size_t)N * HID + j] = gsum[j] * (1.0f / (float)N);
}

// ---------------------------------------------------------------------------
extern "C" void kernel_launch(void* const* d_in, const int* in_sizes, int n_in,
                              void* d_out, int out_size, void* d_ws, size_t ws_size,
                              hipStream_t stream)
{
    const float* feat      = (const float*)d_in[0];
    const int*   role_ids  = (const int*)  d_in[1];
    const int*   b2b_src   = (const int*)  d_in[2];
    const int*   b2b_dst   = (const int*)  d_in[3];
    const float* b2b_w     = (const float*)d_in[4];
    const int*   p2b_block = (const int*)  d_in[5];
    const float* p2b_w     = (const float*)d_in[6];
    const float* role_emb  = (const float*)d_in[7];
    const float* idx_emb   = (const float*)d_in[8];
    const float* W1        = (const float*)d_in[9];
    const float* b1        = (const float*)d_in[10];
    const float* W2        = (const float*)d_in[11];
    const float* b2        = (const float*)d_in[12];
    const float* M1        = (const float*)d_in[13];
    const float* mb1       = (const float*)d_in[14];
    const float* M2        = (const float*)d_in[15];
    const float* mb2       = (const float*)d_in[16];
    const float* ln_g      = (const float*)d_in[17];
    const float* ln_b      = (const float*)d_in[18];

    const int N = in_sizes[1];
    const int E = in_sizes[2];
    const int P = in_sizes[5];

    float* out = (float*)d_out;

    // workspace layout (16B aligned)
    char* ws = (char*)d_ws;
    size_t embBytes  = (size_t)N * HID * sizeof(float);    // 51.2 MB
    size_t embhBytes = (size_t)N * HID * sizeof(ushort);   // 25.6 MB
    size_t aggBytes  = (size_t)N * HID * sizeof(float);    // 51.2 MB
    size_t entBytes  = (size_t)2 * E * sizeof(uint);       // 8 MB
    size_t vecBytes  = (size_t)N * sizeof(int);            // 400 KB

    float*  emb     = (float*)ws;   ws += embBytes;
    float*  agg     = (float*)ws;   ws += aggBytes;
    ushort* embh    = (ushort*)ws;  ws += embhBytes;
    uint*   entries = (uint*)ws;    ws += entBytes;
    int*    startA  = (int*)ws;     ws += vecBytes;
    int*    cursor  = (int*)ws;     ws += vecBytes;
    int*    count   = (int*)ws;     ws += vecBytes;
    float*  pw      = (float*)ws;   ws += vecBytes;
    float*  gsum    = (float*)ws;   ws += HID * sizeof(float);

    // zero count | pw | gsum (contiguous)
    hipMemsetAsync(count, 0, 2 * vecBytes + HID * sizeof(float), stream);

    const int nBlocksTile = (N + TILE - 1) / TILE;

    k_embed_mlp<<<nBlocksTile, 256, 0, stream>>>(
        feat, role_ids, role_emb, idx_emb, W1, b1, W2, b2, emb, embh, N);

    k_count_pw<<<2048, 256, 0, stream>>>(b2b_src, b2b_dst, count,
                                         p2b_block, p2b_w, pw, E, P);

    k_scan<<<1, 1024, 0, stream>>>(count, startA, cursor, N);

    k_scatter<<<2048, 256, 0, stream>>>(b2b_src, b2b_dst, b2b_w, cursor, entries, E);

    k_gather<<<nBlocksTile, 256, 0, stream>>>(
        embh, emb, entries, startA, count, pw, agg, N);

    k_msg_ln<<<nBlocksTile, 256, 0, stream>>>(
        agg, emb, M1, mb1, M2, mb2, ln_g, ln_b, out, gsum, N);

    k_graph<<<1, HID, 0, stream>>>(gsum, out, N);
}

// Round 5
// 702.387 us; speedup vs baseline: 3.0033x; 2.6479x over previous
//
#include <hip/hip_runtime.h>

#define FEAT 14
#define ROLE_DIM 16
#define IDX_DIM 8
#define IN_DIM 38       // 14 + 16 + 8
#define HID 128
#define IDX_VOCAB 1024
#define TILE 32

typedef __attribute__((ext_vector_type(8))) short short8;
typedef __attribute__((ext_vector_type(4))) float f32x4;

// bf16 round-to-nearest-even pack
__device__ __forceinline__ ushort f2bf(float f) {
    uint u = __float_as_uint(f);
    return (ushort)((u + 0x7FFFu + ((u >> 16) & 1u)) >> 16);
}

// ---------------------------------------------------------------------------
// Prep: bf16 + transpose of the 4 weight matrices.
// W1t [128 cols][64 k] (k>=38 zero-padded); W2t/M1t/M2t [128 cols][128 k].
// ---------------------------------------------------------------------------
__global__ void k_prep(const float* __restrict__ W1, const float* __restrict__ W2,
                       const float* __restrict__ M1, const float* __restrict__ M2,
                       ushort* __restrict__ W1t, ushort* __restrict__ W2t,
                       ushort* __restrict__ M1t, ushort* __restrict__ M2t)
{
    int t = blockIdx.x * 256 + threadIdx.x;
    if (t < 8192) {                    // W1t: 128 x 64
        int c = t >> 6, k = t & 63;
        W1t[t] = (k < IN_DIM) ? f2bf(W1[k * HID + c]) : (ushort)0;
    } else if (t < 24576) {            // W2t: 128 x 128
        int u = t - 8192; int c = u >> 7, k = u & 127;
        W2t[u] = f2bf(W2[k * HID + c]);
    } else if (t < 40960) {            // M1t
        int u = t - 24576; int c = u >> 7, k = u & 127;
        M1t[u] = f2bf(M1[k * HID + c]);
    } else if (t < 57344) {            // M2t
        int u = t - 40960; int c = u >> 7, k = u & 127;
        M2t[u] = f2bf(M2[k * HID + c]);
    }
}

// ---------------------------------------------------------------------------
// MFMA MLP A: emb = relu(relu(x@W1+b1)@W2+b2); writes emb f32 + embh bf16.
// 64 rows/block, 4 waves; wave w: rows w*16..w*16+15, all 128 cols.
// LDS: [0,32K) weights (col-major rows, 256B stride, XOR-swizzled 16B slots),
//      [32K,48K) activations (row stride 256B, same swizzle).
// ---------------------------------------------------------------------------
#define LDSA 32768

__global__ __launch_bounds__(256) void k_embed_mlp(
    const float* __restrict__ feat, const int* __restrict__ role_ids,
    const float* __restrict__ role_emb, const float* __restrict__ idx_emb,
    const ushort* __restrict__ W1t, const float* __restrict__ b1,
    const ushort* __restrict__ W2t, const float* __restrict__ b2,
    float* __restrict__ emb, ushort* __restrict__ embh, int N)
{
    __shared__ char lds[49152];
    const int tid = threadIdx.x;
    const int w = tid >> 6, l = tid & 63;
    const int li = l & 15, hi = l >> 4;
    const int base = blockIdx.x * 64;

    // stage W1t (16KB) : [128 cols][64 k] -> 8 x 16B chunks per col
    for (int c = 0; c < 4; ++c) {
        int idx = c * 256 + tid;            // 0..1023 (16B chunks)
        int col = idx >> 3, ch = idx & 7;   // col 0..127, ch 0..7  (FIXED)
        uint4 v = *(const uint4*)(W1t + col * 64 + ch * 8);
        *(uint4*)(lds + col * 256 + ((ch * 16) ^ ((col & 7) << 4))) = v;
    }
    // build x-tile [64 rows][64 k] bf16 at LDSA
    {
        int row = tid >> 2, kq = (tid & 3) * 16;
        int gr = base + row; if (gr >= N) gr = N - 1;
        int rid = role_ids[gr];
        float xv[16];
        #pragma unroll
        for (int j = 0; j < 16; ++j) {
            int k = kq + j;
            float v = 0.0f;
            if (k < FEAT)                 v = feat[gr * FEAT + k];
            else if (k < FEAT + ROLE_DIM) v = role_emb[rid * ROLE_DIM + (k - FEAT)];
            else if (k < IN_DIM)          v = idx_emb[(gr & (IDX_VOCAB - 1)) * IDX_DIM + (k - FEAT - ROLE_DIM)];
            xv[j] = v;
        }
        uint p[8];
        #pragma unroll
        for (int j = 0; j < 8; ++j)
            p[j] = (uint)f2bf(xv[2 * j]) | ((uint)f2bf(xv[2 * j + 1]) << 16);
        char* db = lds + LDSA + row * 256;
        int sw = (row & 7) << 4;
        *(uint4*)(db + ((kq * 2) ^ sw))      = make_uint4(p[0], p[1], p[2], p[3]);
        *(uint4*)(db + ((kq * 2 + 16) ^ sw)) = make_uint4(p[4], p[5], p[6], p[7]);
    }
    __syncthreads();

    // phase 1: K=64
    f32x4 C[8];
    #pragma unroll
    for (int ct = 0; ct < 8; ++ct) C[ct] = (f32x4){0.f, 0.f, 0.f, 0.f};
    {
        const int arow = w * 16 + li;
        const int asw = (arow & 7) << 4;
        #pragma unroll
        for (int ks = 0; ks < 2; ++ks) {
            short8 a = *(short8*)(lds + LDSA + arow * 256 + ((ks * 64 + hi * 16) ^ asw));
            #pragma unroll
            for (int ct = 0; ct < 8; ++ct) {
                int bcol = ct * 16 + li;
                short8 b = *(short8*)(lds + bcol * 256 + ((ks * 64 + hi * 16) ^ ((bcol & 7) << 4)));
                C[ct] = __builtin_amdgcn_mfma_f32_16x16x32_bf16(a, b, C[ct], 0, 0, 0);
            }
        }
    }
    __syncthreads();

    // H = relu(C+b1) bf16 -> LDSA; stage W2t (32KB)
    #pragma unroll
    for (int ct = 0; ct < 8; ++ct) {
        int col = ct * 16 + li;
        float bv = b1[col];
        #pragma unroll
        for (int r = 0; r < 4; ++r) {
            int hrow = w * 16 + hi * 4 + r;
            float h = fmaxf(C[ct][r] + bv, 0.0f);
            *(ushort*)(lds + LDSA + hrow * 256 + ((col * 2) ^ ((hrow & 7) << 4))) = f2bf(h);
        }
    }
    for (int c = 0; c < 8; ++c) {
        int idx = c * 256 + tid;            // 0..2047
        int col = idx >> 4, ch = idx & 15;
        uint4 v = *(const uint4*)(W2t + col * 128 + ch * 8);
        *(uint4*)(lds + col * 256 + ((ch * 16) ^ ((col & 7) << 4))) = v;
    }
    __syncthreads();

    // phase 2: K=128
    f32x4 C2[8];
    #pragma unroll
    for (int ct = 0; ct < 8; ++ct) C2[ct] = (f32x4){0.f, 0.f, 0.f, 0.f};
    {
        const int arow = w * 16 + li;
        const int asw = (arow & 7) << 4;
        #pragma unroll
        for (int ks = 0; ks < 4; ++ks) {
            short8 a = *(short8*)(lds + LDSA + arow * 256 + ((ks * 64 + hi * 16) ^ asw));
            #pragma unroll
            for (int ct = 0; ct < 8; ++ct) {
                int bcol = ct * 16 + li;
                short8 b = *(short8*)(lds + bcol * 256 + ((ks * 64 + hi * 16) ^ ((bcol & 7) << 4)));
                C2[ct] = __builtin_amdgcn_mfma_f32_16x16x32_bf16(a, b, C2[ct], 0, 0, 0);
            }
        }
    }

    // epilogue: o = relu(C2+b2); store emb f32 + embh bf16
    #pragma unroll
    for (int ct = 0; ct < 8; ++ct) {
        int col = ct * 16 + li;
        float bv = b2[col];
        #pragma unroll
        for (int r = 0; r < 4; ++r) {
            int gr = base + w * 16 + hi * 4 + r;
            if (gr < N) {
                float o = fmaxf(C2[ct][r] + bv, 0.0f);
                emb[(size_t)gr * 128 + col] = o;
                embh[(size_t)gr * 128 + col] = f2bf(o);
            }
        }
    }
}

// ---------------------------------------------------------------------------
// degree count + pin-weight histogram
// ---------------------------------------------------------------------------
__global__ void k_count_pw(const int* __restrict__ src, const int* __restrict__ dst,
                           int* __restrict__ count,
                           const int* __restrict__ pb, const float* __restrict__ pv,
                           float* __restrict__ pw, int E, int P)
{
    int i = blockIdx.x * blockDim.x + threadIdx.x;
    int stride = gridDim.x * blockDim.x;
    int M = E > P ? E : P;
    for (; i < M; i += stride) {
        if (i < E) {
            atomicAdd(&count[src[i]], 1);
            atomicAdd(&count[dst[i]], 1);
        }
        if (i < P)
            atomicAdd(&pw[pb[i]], pv[i]);
    }
}

__global__ __launch_bounds__(1024) void k_scan(const int* __restrict__ count,
    int* __restrict__ start, int* __restrict__ cursor, int N)
{
    __shared__ int tsum[1024];
    const int tid = threadIdx.x;
    const int per = (N + 1023) / 1024;
    const int lo = tid * per;
    const int hi = (lo + per) < N ? (lo + per) : N;
    int s = 0;
    for (int i = lo; i < hi; ++i) s += count[i];
    tsum[tid] = s;
    __syncthreads();
    for (int off = 1; off < 1024; off <<= 1) {
        int v = (tid >= off) ? tsum[tid - off] : 0;
        __syncthreads();
        tsum[tid] += v;
        __syncthreads();
    }
    int run = (tid == 0) ? 0 : tsum[tid - 1];
    for (int i = lo; i < hi; ++i) {
        start[i] = run;
        cursor[i] = run;
        run += count[i];
    }
}

// entries packed: (nbr << 15) | round(w * 32767)
__global__ void k_scatter(const int* __restrict__ src, const int* __restrict__ dst,
                          const float* __restrict__ w, int* __restrict__ cursor,
                          uint* __restrict__ entries, int E)
{
    int i = blockIdx.x * blockDim.x + threadIdx.x;
    int stride = gridDim.x * blockDim.x;
    for (; i < E; i += stride) {
        int s = src[i];
        int d = dst[i];
        uint q = (uint)(w[i] * 32767.0f + 0.5f);
        int p0 = atomicAdd(&cursor[s], 1);
        entries[p0] = ((uint)d << 15) | q;
        int p1 = atomicAdd(&cursor[d], 1);
        entries[p1] = ((uint)s << 15) | q;
    }
}

// ---------------------------------------------------------------------------
// gather: aggh = bf16( emb*pw + sum_nb bf16(emb[nb])*w )
// ---------------------------------------------------------------------------
__global__ __launch_bounds__(256) void k_gather(
    const ushort* __restrict__ embh, const float* __restrict__ emb,
    const uint* __restrict__ entries, const int* __restrict__ start,
    const int* __restrict__ count, const float* __restrict__ pw,
    ushort* __restrict__ aggh, int N)
{
    const int tid = threadIdx.x;
    const int node = blockIdx.x * TILE + (tid >> 3);
    const int cg = tid & 7;
    const int c0 = cg * 16;
    if (node >= N) return;

    float acc[16];
    {
        float pwn = pw[node];
        const float4* e4p = (const float4*)(emb + (size_t)node * HID + c0);
        #pragma unroll
        for (int q = 0; q < 4; ++q) {
            float4 e4 = e4p[q];
            acc[q*4+0] = e4.x * pwn; acc[q*4+1] = e4.y * pwn;
            acc[q*4+2] = e4.z * pwn; acc[q*4+3] = e4.w * pwn;
        }
    }

    const int st  = start[node];
    const int deg = count[node];
    const uint* ep = entries + st;
    #pragma unroll 4
    for (int i = 0; i < deg; ++i) {
        uint en = ep[i];
        int nb   = (int)(en >> 15);
        float wt = (float)(en & 32767u) * (1.0f / 32767.0f);
        const uint4* r = (const uint4*)(embh + ((size_t)nb << 7) + c0);
        uint4 u0 = r[0];
        uint4 u1 = r[1];
        uint uu[8] = {u0.x, u0.y, u0.z, u0.w, u1.x, u1.y, u1.z, u1.w};
        #pragma unroll
        for (int j = 0; j < 8; ++j) {
            float lo = __uint_as_float(uu[j] << 16);
            float hi = __uint_as_float(uu[j] & 0xffff0000u);
            acc[2*j]   = fmaf(lo, wt, acc[2*j]);
            acc[2*j+1] = fmaf(hi, wt, acc[2*j+1]);
        }
    }

    uint p[8];
    #pragma unroll
    for (int j = 0; j < 8; ++j)
        p[j] = (uint)f2bf(acc[2*j]) | ((uint)f2bf(acc[2*j+1]) << 16);
    uint4* ap = (uint4*)(aggh + (size_t)node * HID + c0);
    ap[0] = make_uint4(p[0], p[1], p[2], p[3]);
    ap[1] = make_uint4(p[4], p[5], p[6], p[7]);
}

// ---------------------------------------------------------------------------
// MFMA MLP B: m = relu(aggh@M1+mb1)@M2+mb2; out = LN(emb+m); gsum partials.
// ---------------------------------------------------------------------------
#define LDSS 49152  // wsum f32[4][128] after W(32K)+A(16K)

__global__ __launch_bounds__(256) void k_msg_ln(
    const ushort* __restrict__ aggh, const float* __restrict__ emb,
    const ushort* __restrict__ M1t, const ushort* __restrict__ M2t,
    const float* __restrict__ mb1, const float* __restrict__ mb2,
    const float* __restrict__ ln_g, const float* __restrict__ ln_b,
    float* __restrict__ out, float* __restrict__ gsum, int N)
{
    __shared__ char lds[51200];
    const int tid = threadIdx.x;
    const int w = tid >> 6, l = tid & 63;
    const int li = l & 15, hi = l >> 4;
    const int base = blockIdx.x * 64;

    // stage M1t (32KB) + A-tile from aggh (16KB)
    for (int c = 0; c < 8; ++c) {
        int idx = c * 256 + tid;
        int col = idx >> 4, ch = idx & 15;
        uint4 v = *(const uint4*)(M1t + col * 128 + ch * 8);
        *(uint4*)(lds + col * 256 + ((ch * 16) ^ ((col & 7) << 4))) = v;
    }
    for (int c = 0; c < 4; ++c) {
        int idx = c * 256 + tid;
        int row = idx >> 4, ch = idx & 15;
        int gr = base + row; if (gr >= N) gr = N - 1;
        uint4 v = *(const uint4*)(aggh + (size_t)gr * 128 + ch * 8);
        *(uint4*)(lds + LDSA + row * 256 + ((ch * 16) ^ ((row & 7) << 4))) = v;
    }
    __syncthreads();

    // phase 1: K=128
    f32x4 C[8];
    #pragma unroll
    for (int ct = 0; ct < 8; ++ct) C[ct] = (f32x4){0.f, 0.f, 0.f, 0.f};
    {
        const int arow = w * 16 + li;
        const int asw = (arow & 7) << 4;
        #pragma unroll
        for (int ks = 0; ks < 4; ++ks) {
            short8 a = *(short8*)(lds + LDSA + arow * 256 + ((ks * 64 + hi * 16) ^ asw));
            #pragma unroll
            for (int ct = 0; ct < 8; ++ct) {
                int bcol = ct * 16 + li;
                short8 b = *(short8*)(lds + bcol * 256 + ((ks * 64 + hi * 16) ^ ((bcol & 7) << 4)));
                C[ct] = __builtin_amdgcn_mfma_f32_16x16x32_bf16(a, b, C[ct], 0, 0, 0);
            }
        }
    }
    __syncthreads();

    // H = relu(C+mb1) bf16 -> LDSA; stage M2t
    #pragma unroll
    for (int ct = 0; ct < 8; ++ct) {
        int col = ct * 16 + li;
        float bv = mb1[col];
        #pragma unroll
        for (int r = 0; r < 4; ++r) {
            int hrow = w * 16 + hi * 4 + r;
            float h = fmaxf(C[ct][r] + bv, 0.0f);
            *(ushort*)(lds + LDSA + hrow * 256 + ((col * 2) ^ ((hrow & 7) << 4))) = f2bf(h);
        }
    }
    for (int c = 0; c < 8; ++c) {
        int idx = c * 256 + tid;
        int col = idx >> 4, ch = idx & 15;
        uint4 v = *(const uint4*)(M2t + col * 128 + ch * 8);
        *(uint4*)(lds + col * 256 + ((ch * 16) ^ ((col & 7) << 4))) = v;
    }
    __syncthreads();

    // phase 2: K=128
    f32x4 C2[8];
    #pragma unroll
    for (int ct = 0; ct < 8; ++ct) C2[ct] = (f32x4){0.f, 0.f, 0.f, 0.f};
    {
        const int arow = w * 16 + li;
        const int asw = (arow & 7) << 4;
        #pragma unroll
        for (int ks = 0; ks < 4; ++ks) {
            short8 a = *(short8*)(lds + LDSA + arow * 256 + ((ks * 64 + hi * 16) ^ asw));
            #pragma unroll
            for (int ct = 0; ct < 8; ++ct) {
                int bcol = ct * 16 + li;
                short8 b = *(short8*)(lds + bcol * 256 + ((ks * 64 + hi * 16) ^ ((bcol & 7) << 4)));
                C2[ct] = __builtin_amdgcn_mfma_f32_16x16x32_bf16(a, b, C2[ct], 0, 0, 0);
            }
        }
    }

    // epilogue: y = C2 + mb2 + emb; LayerNorm per row; store; graph partials
    float y[8][4];
    #pragma unroll
    for (int ct = 0; ct < 8; ++ct) {
        int col = ct * 16 + li;
        float bv = mb2[col];
        #pragma unroll
        for (int r = 0; r < 4; ++r) {
            int gr = base + w * 16 + hi * 4 + r;
            int grc = gr < N ? gr : N - 1;
            y[ct][r] = C2[ct][r] + bv + emb[(size_t)grc * 128 + col];
        }
    }
    float rs[4] = {0, 0, 0, 0}, rq[4] = {0, 0, 0, 0};
    #pragma unroll
    for (int ct = 0; ct < 8; ++ct)
        #pragma unroll
        for (int r = 0; r < 4; ++r) { rs[r] += y[ct][r]; rq[r] += y[ct][r] * y[ct][r]; }
    #pragma unroll
    for (int m = 1; m < 16; m <<= 1) {
        #pragma unroll
        for (int r = 0; r < 4; ++r) {
            rs[r] += __shfl_xor(rs[r], m);
            rq[r] += __shfl_xor(rq[r], m);
        }
    }
    float mu[4], rstd[4];
    #pragma unroll
    for (int r = 0; r < 4; ++r) {
        mu[r] = rs[r] * (1.0f / HID);
        float var = rq[r] * (1.0f / HID) - mu[r] * mu[r];
        rstd[r] = rsqrtf(var + 1e-5f);
    }
    float cs[8];
    #pragma unroll
    for (int ct = 0; ct < 8; ++ct) {
        cs[ct] = 0.0f;
        int col = ct * 16 + li;
        float g = ln_g[col], bb = ln_b[col];
        #pragma unroll
        for (int r = 0; r < 4; ++r) {
            int gr = base + w * 16 + hi * 4 + r;
            float o = (y[ct][r] - mu[r]) * rstd[r] * g + bb;
            if (gr < N) {
                out[(size_t)gr * 128 + col] = o;
                cs[ct] += o;
            }
        }
    }
    #pragma unroll
    for (int m = 16; m < 64; m <<= 1) {
        #pragma unroll
        for (int ct = 0; ct < 8; ++ct) cs[ct] += __shfl_xor(cs[ct], m);
    }
    float* wsum = (float*)(lds + LDSS);
    if (hi == 0) {
        #pragma unroll
        for (int ct = 0; ct < 8; ++ct) wsum[w * 128 + ct * 16 + li] = cs[ct];
    }
    __syncthreads();
    if (tid < 128) {
        float s = wsum[tid] + wsum[128 + tid] + wsum[256 + tid] + wsum[384 + tid];
        atomicAdd(&gsum[tid], s);
    }
}

// ---------------------------------------------------------------------------
__global__ void k_graph(const float* __restrict__ gsum, float* __restrict__ out,
                        int N)
{
    int j = threadIdx.x;
    out[(size_t)N * HID + j] = gsum[j] * (1.0f / (float)N);
}

// ---------------------------------------------------------------------------
extern "C" void kernel_launch(void* const* d_in, const int* in_sizes, int n_in,
                              void* d_out, int out_size, void* d_ws, size_t ws_size,
                              hipStream_t stream)
{
    const float* feat      = (const float*)d_in[0];
    const int*   role_ids  = (const int*)  d_in[1];
    const int*   b2b_src   = (const int*)  d_in[2];
    const int*   b2b_dst   = (const int*)  d_in[3];
    const float* b2b_w     = (const float*)d_in[4];
    const int*   p2b_block = (const int*)  d_in[5];
    const float* p2b_w     = (const float*)d_in[6];
    const float* role_emb  = (const float*)d_in[7];
    const float* idx_emb   = (const float*)d_in[8];
    const float* W1        = (const float*)d_in[9];
    const float* b1        = (const float*)d_in[10];
    const float* W2        = (const float*)d_in[11];
    const float* b2        = (const float*)d_in[12];
    const float* M1        = (const float*)d_in[13];
    const float* mb1       = (const float*)d_in[14];
    const float* M2        = (const float*)d_in[15];
    const float* mb2       = (const float*)d_in[16];
    const float* ln_g      = (const float*)d_in[17];
    const float* ln_b      = (const float*)d_in[18];

    const int N = in_sizes[1];
    const int E = in_sizes[2];
    const int P = in_sizes[5];

    float* out = (float*)d_out;

    // workspace layout (16B aligned throughout)
    char* ws = (char*)d_ws;
    size_t embBytes  = (size_t)N * HID * sizeof(float);    // 51.2 MB
    size_t embhBytes = (size_t)N * HID * sizeof(ushort);   // 25.6 MB
    size_t entBytes  = (size_t)2 * E * sizeof(uint);       // 8 MB
    size_t vecBytes  = (size_t)N * sizeof(int);            // 400 KB

    float*  emb     = (float*)ws;   ws += embBytes;
    ushort* embh    = (ushort*)ws;  ws += embhBytes;
    ushort* aggh    = (ushort*)ws;  ws += embhBytes;
    uint*   entries = (uint*)ws;    ws += entBytes;
    int*    startA  = (int*)ws;     ws += vecBytes;
    int*    cursor  = (int*)ws;     ws += vecBytes;
    int*    count   = (int*)ws;     ws += vecBytes;
    float*  pw      = (float*)ws;   ws += vecBytes;
    float*  gsum    = (float*)ws;   ws += 512;
    ushort* W1t     = (ushort*)ws;  ws += 8192  * sizeof(ushort);
    ushort* W2t     = (ushort*)ws;  ws += 16384 * sizeof(ushort);
    ushort* M1t     = (ushort*)ws;  ws += 16384 * sizeof(ushort);
    ushort* M2t     = (ushort*)ws;  ws += 16384 * sizeof(ushort);

    // zero count | pw | gsum (contiguous)
    hipMemsetAsync(count, 0, 2 * vecBytes + 512, stream);

    const int nBlocks64 = (N + 63) / 64;

    k_prep<<<224, 256, 0, stream>>>(W1, W2, M1, M2, W1t, W2t, M1t, M2t);

    k_embed_mlp<<<nBlocks64, 256, 0, stream>>>(
        feat, role_ids, role_emb, idx_emb, W1t, b1, W2t, b2, emb, embh, N);

    k_count_pw<<<2048, 256, 0, stream>>>(b2b_src, b2b_dst, count,
                                         p2b_block, p2b_w, pw, E, P);

    k_scan<<<1, 1024, 0, stream>>>(count, startA, cursor, N);

    k_scatter<<<2048, 256, 0, stream>>>(b2b_src, b2b_dst, b2b_w, cursor, entries, E);

    k_gather<<<(N + TILE - 1) / TILE, 256, 0, stream>>>(
        embh, emb, entries, startA, count, pw, aggh, N);

    k_msg_ln<<<nBlocks64, 256, 0, stream>>>(
        aggh, emb, M1t, M2t, mb1, mb2, ln_g, ln_b, out, gsum, N);

    k_graph<<<1, HID, 0, stream>>>(gsum, out, N);
}

// Round 6
// 476.289 us; speedup vs baseline: 4.4290x; 1.4747x over previous
//
#include <hip/hip_runtime.h>

#define FEAT 14
#define ROLE_DIM 16
#define IDX_DIM 8
#define IN_DIM 38       // 14 + 16 + 8
#define HID 128
#define IDX_VOCAB 1024
#define TILE 32
#define SCAN_C 2048     // counts per scan block (256 threads x 8)

typedef __attribute__((ext_vector_type(8))) short short8;
typedef __attribute__((ext_vector_type(4))) float f32x4;

// bf16 round-to-nearest-even pack
__device__ __forceinline__ ushort f2bf(float f) {
    uint u = __float_as_uint(f);
    return (ushort)((u + 0x7FFFu + ((u >> 16) & 1u)) >> 16);
}

// ---------------------------------------------------------------------------
// Prep: bf16 + transpose of the 4 weight matrices.
// ---------------------------------------------------------------------------
__global__ void k_prep(const float* __restrict__ W1, const float* __restrict__ W2,
                       const float* __restrict__ M1, const float* __restrict__ M2,
                       ushort* __restrict__ W1t, ushort* __restrict__ W2t,
                       ushort* __restrict__ M1t, ushort* __restrict__ M2t)
{
    int t = blockIdx.x * 256 + threadIdx.x;
    if (t < 8192) {                    // W1t: 128 x 64
        int c = t >> 6, k = t & 63;
        W1t[t] = (k < IN_DIM) ? f2bf(W1[k * HID + c]) : (ushort)0;
    } else if (t < 24576) {            // W2t: 128 x 128
        int u = t - 8192; int c = u >> 7, k = u & 127;
        W2t[u] = f2bf(W2[k * HID + c]);
    } else if (t < 40960) {            // M1t
        int u = t - 24576; int c = u >> 7, k = u & 127;
        M1t[u] = f2bf(M1[k * HID + c]);
    } else if (t < 57344) {            // M2t
        int u = t - 40960; int c = u >> 7, k = u & 127;
        M2t[u] = f2bf(M2[k * HID + c]);
    }
}

// ---------------------------------------------------------------------------
// MFMA MLP A: emb = relu(relu(x@W1+b1)@W2+b2); writes emb f32 + embh bf16.
// ---------------------------------------------------------------------------
#define LDSA 32768

__global__ __launch_bounds__(256) void k_embed_mlp(
    const float* __restrict__ feat, const int* __restrict__ role_ids,
    const float* __restrict__ role_emb, const float* __restrict__ idx_emb,
    const ushort* __restrict__ W1t, const float* __restrict__ b1,
    const ushort* __restrict__ W2t, const float* __restrict__ b2,
    float* __restrict__ emb, ushort* __restrict__ embh, int N)
{
    __shared__ char lds[49152];
    const int tid = threadIdx.x;
    const int w = tid >> 6, l = tid & 63;
    const int li = l & 15, hi = l >> 4;
    const int base = blockIdx.x * 64;

    // stage W1t (16KB) : [128 cols][64 k] -> 8 x 16B chunks per col
    for (int c = 0; c < 4; ++c) {
        int idx = c * 256 + tid;            // 0..1023 (16B chunks)
        int col = idx >> 3, ch = idx & 7;
        uint4 v = *(const uint4*)(W1t + col * 64 + ch * 8);
        *(uint4*)(lds + col * 256 + ((ch * 16) ^ ((col & 7) << 4))) = v;
    }
    // build x-tile [64 rows][64 k] bf16 at LDSA
    {
        int row = tid >> 2, kq = (tid & 3) * 16;
        int gr = base + row; if (gr >= N) gr = N - 1;
        int rid = role_ids[gr];
        float xv[16];
        #pragma unroll
        for (int j = 0; j < 16; ++j) {
            int k = kq + j;
            float v = 0.0f;
            if (k < FEAT)                 v = feat[gr * FEAT + k];
            else if (k < FEAT + ROLE_DIM) v = role_emb[rid * ROLE_DIM + (k - FEAT)];
            else if (k < IN_DIM)          v = idx_emb[(gr & (IDX_VOCAB - 1)) * IDX_DIM + (k - FEAT - ROLE_DIM)];
            xv[j] = v;
        }
        uint p[8];
        #pragma unroll
        for (int j = 0; j < 8; ++j)
            p[j] = (uint)f2bf(xv[2 * j]) | ((uint)f2bf(xv[2 * j + 1]) << 16);
        char* db = lds + LDSA + row * 256;
        int sw = (row & 7) << 4;
        *(uint4*)(db + ((kq * 2) ^ sw))      = make_uint4(p[0], p[1], p[2], p[3]);
        *(uint4*)(db + ((kq * 2 + 16) ^ sw)) = make_uint4(p[4], p[5], p[6], p[7]);
    }
    __syncthreads();

    // phase 1: K=64
    f32x4 C[8];
    #pragma unroll
    for (int ct = 0; ct < 8; ++ct) C[ct] = (f32x4){0.f, 0.f, 0.f, 0.f};
    {
        const int arow = w * 16 + li;
        const int asw = (arow & 7) << 4;
        #pragma unroll
        for (int ks = 0; ks < 2; ++ks) {
            short8 a = *(short8*)(lds + LDSA + arow * 256 + ((ks * 64 + hi * 16) ^ asw));
            #pragma unroll
            for (int ct = 0; ct < 8; ++ct) {
                int bcol = ct * 16 + li;
                short8 b = *(short8*)(lds + bcol * 256 + ((ks * 64 + hi * 16) ^ ((bcol & 7) << 4)));
                C[ct] = __builtin_amdgcn_mfma_f32_16x16x32_bf16(a, b, C[ct], 0, 0, 0);
            }
        }
    }
    __syncthreads();

    // H = relu(C+b1) bf16 -> LDSA; stage W2t (32KB)
    #pragma unroll
    for (int ct = 0; ct < 8; ++ct) {
        int col = ct * 16 + li;
        float bv = b1[col];
        #pragma unroll
        for (int r = 0; r < 4; ++r) {
            int hrow = w * 16 + hi * 4 + r;
            float h = fmaxf(C[ct][r] + bv, 0.0f);
            *(ushort*)(lds + LDSA + hrow * 256 + ((col * 2) ^ ((hrow & 7) << 4))) = f2bf(h);
        }
    }
    for (int c = 0; c < 8; ++c) {
        int idx = c * 256 + tid;            // 0..2047
        int col = idx >> 4, ch = idx & 15;
        uint4 v = *(const uint4*)(W2t + col * 128 + ch * 8);
        *(uint4*)(lds + col * 256 + ((ch * 16) ^ ((col & 7) << 4))) = v;
    }
    __syncthreads();

    // phase 2: K=128
    f32x4 C2[8];
    #pragma unroll
    for (int ct = 0; ct < 8; ++ct) C2[ct] = (f32x4){0.f, 0.f, 0.f, 0.f};
    {
        const int arow = w * 16 + li;
        const int asw = (arow & 7) << 4;
        #pragma unroll
        for (int ks = 0; ks < 4; ++ks) {
            short8 a = *(short8*)(lds + LDSA + arow * 256 + ((ks * 64 + hi * 16) ^ asw));
            #pragma unroll
            for (int ct = 0; ct < 8; ++ct) {
                int bcol = ct * 16 + li;
                short8 b = *(short8*)(lds + bcol * 256 + ((ks * 64 + hi * 16) ^ ((bcol & 7) << 4)));
                C2[ct] = __builtin_amdgcn_mfma_f32_16x16x32_bf16(a, b, C2[ct], 0, 0, 0);
            }
        }
    }

    // epilogue: o = relu(C2+b2); store emb f32 + embh bf16
    #pragma unroll
    for (int ct = 0; ct < 8; ++ct) {
        int col = ct * 16 + li;
        float bv = b2[col];
        #pragma unroll
        for (int r = 0; r < 4; ++r) {
            int gr = base + w * 16 + hi * 4 + r;
            if (gr < N) {
                float o = fmaxf(C2[ct][r] + bv, 0.0f);
                emb[(size_t)gr * 128 + col] = o;
                embh[(size_t)gr * 128 + col] = f2bf(o);
            }
        }
    }
}

// ---------------------------------------------------------------------------
// degree count + pin-weight histogram
// ---------------------------------------------------------------------------
__global__ void k_count_pw(const int* __restrict__ src, const int* __restrict__ dst,
                           int* __restrict__ count,
                           const int* __restrict__ pb, const float* __restrict__ pv,
                           float* __restrict__ pw, int E, int P)
{
    int i = blockIdx.x * blockDim.x + threadIdx.x;
    int stride = gridDim.x * blockDim.x;
    int M = E > P ? E : P;
    for (; i < M; i += stride) {
        if (i < E) {
            atomicAdd(&count[src[i]], 1);
            atomicAdd(&count[dst[i]], 1);
        }
        if (i < P)
            atomicAdd(&pw[pb[i]], pv[i]);
    }
}

// ---------------------------------------------------------------------------
// Two-level scan: k_scan1 (block sums) -> k_scan2 (scan of block sums) ->
// k_scan3 (in-block scan + write start/cursor).
// ---------------------------------------------------------------------------
__global__ __launch_bounds__(256) void k_scan1(const int* __restrict__ count,
                                               int* __restrict__ bsum, int N)
{
    __shared__ int wls[4];
    const int tid = threadIdx.x;
    const int base = blockIdx.x * SCAN_C + tid * 8;
    int s = 0;
    if (base + 8 <= N) {
        int4 a = *(const int4*)(count + base);
        int4 b = *(const int4*)(count + base + 4);
        s = a.x + a.y + a.z + a.w + b.x + b.y + b.z + b.w;
    } else {
        for (int j = 0; j < 8; ++j) {
            int i = base + j;
            if (i < N) s += count[i];
        }
    }
    #pragma unroll
    for (int m = 1; m < 64; m <<= 1) s += __shfl_xor(s, m);
    if ((tid & 63) == 0) wls[tid >> 6] = s;
    __syncthreads();
    if (tid == 0) bsum[blockIdx.x] = wls[0] + wls[1] + wls[2] + wls[3];
}

__global__ __launch_bounds__(1024) void k_scan2(const int* __restrict__ bsum,
                                                int* __restrict__ boff, int B)
{
    __shared__ int t[1024];
    const int tid = threadIdx.x;
    t[tid] = (tid < B) ? bsum[tid] : 0;
    __syncthreads();
    for (int off = 1; off < 1024; off <<= 1) {
        int v = (tid >= off) ? t[tid - off] : 0;
        __syncthreads();
        t[tid] += v;
        __syncthreads();
    }
    if (tid < B) boff[tid] = (tid == 0) ? 0 : t[tid - 1];
}

__global__ __launch_bounds__(256) void k_scan3(const int* __restrict__ count,
    const int* __restrict__ boff, int* __restrict__ start,
    int* __restrict__ cursor, int N)
{
    __shared__ int ts[256];
    const int tid = threadIdx.x;
    const int base = blockIdx.x * SCAN_C + tid * 8;
    int c[8];
    int s = 0;
    #pragma unroll
    for (int j = 0; j < 8; ++j) {
        int i = base + j;
        c[j] = (i < N) ? count[i] : 0;
        s += c[j];
    }
    ts[tid] = s;
    __syncthreads();
    for (int off = 1; off < 256; off <<= 1) {
        int v = (tid >= off) ? ts[tid - off] : 0;
        __syncthreads();
        ts[tid] += v;
        __syncthreads();
    }
    int run = boff[blockIdx.x] + ((tid == 0) ? 0 : ts[tid - 1]);
    #pragma unroll
    for (int j = 0; j < 8; ++j) {
        int i = base + j;
        if (i < N) {
            start[i] = run;
            cursor[i] = run;
            run += c[j];
        }
    }
}

// entries packed: (nbr << 15) | round(w * 32767)
__global__ void k_scatter(const int* __restrict__ src, const int* __restrict__ dst,
                          const float* __restrict__ w, int* __restrict__ cursor,
                          uint* __restrict__ entries, int E)
{
    int i = blockIdx.x * blockDim.x + threadIdx.x;
    int stride = gridDim.x * blockDim.x;
    for (; i < E; i += stride) {
        int s = src[i];
        int d = dst[i];
        uint q = (uint)(w[i] * 32767.0f + 0.5f);
        int p0 = atomicAdd(&cursor[s], 1);
        entries[p0] = ((uint)d << 15) | q;
        int p1 = atomicAdd(&cursor[d], 1);
        entries[p1] = ((uint)s << 15) | q;
    }
}

// ---------------------------------------------------------------------------
// gather: aggh = bf16( emb*pw + sum_nb bf16(emb[nb])*w )
// ---------------------------------------------------------------------------
__global__ __launch_bounds__(256) void k_gather(
    const ushort* __restrict__ embh, const float* __restrict__ emb,
    const uint* __restrict__ entries, const int* __restrict__ start,
    const int* __restrict__ count, const float* __restrict__ pw,
    ushort* __restrict__ aggh, int N)
{
    const int tid = threadIdx.x;
    const int node = blockIdx.x * TILE + (tid >> 3);
    const int cg = tid & 7;
    const int c0 = cg * 16;
    if (node >= N) return;

    float acc[16];
    {
        float pwn = pw[node];
        const float4* e4p = (const float4*)(emb + (size_t)node * HID + c0);
        #pragma unroll
        for (int q = 0; q < 4; ++q) {
            float4 e4 = e4p[q];
            acc[q*4+0] = e4.x * pwn; acc[q*4+1] = e4.y * pwn;
            acc[q*4+2] = e4.z * pwn; acc[q*4+3] = e4.w * pwn;
        }
    }

    const int st  = start[node];
    const int deg = count[node];
    const uint* ep = entries + st;
    #pragma unroll 4
    for (int i = 0; i < deg; ++i) {
        uint en = ep[i];
        int nb   = (int)(en >> 15);
        float wt = (float)(en & 32767u) * (1.0f / 32767.0f);
        const uint4* r = (const uint4*)(embh + ((size_t)nb << 7) + c0);
        uint4 u0 = r[0];
        uint4 u1 = r[1];
        uint uu[8] = {u0.x, u0.y, u0.z, u0.w, u1.x, u1.y, u1.z, u1.w};
        #pragma unroll
        for (int j = 0; j < 8; ++j) {
            float lo = __uint_as_float(uu[j] << 16);
            float hi = __uint_as_float(uu[j] & 0xffff0000u);
            acc[2*j]   = fmaf(lo, wt, acc[2*j]);
            acc[2*j+1] = fmaf(hi, wt, acc[2*j+1]);
        }
    }

    uint p[8];
    #pragma unroll
    for (int j = 0; j < 8; ++j)
        p[j] = (uint)f2bf(acc[2*j]) | ((uint)f2bf(acc[2*j+1]) << 16);
    uint4* ap = (uint4*)(aggh + (size_t)node * HID + c0);
    ap[0] = make_uint4(p[0], p[1], p[2], p[3]);
    ap[1] = make_uint4(p[4], p[5], p[6], p[7]);
}

// ---------------------------------------------------------------------------
// MFMA MLP B: m = relu(aggh@M1+mb1)@M2+mb2; out = LN(emb+m); gsum partials.
// ---------------------------------------------------------------------------
#define LDSS 49152  // wsum f32[4][128] after W(32K)+A(16K)

__global__ __launch_bounds__(256) void k_msg_ln(
    const ushort* __restrict__ aggh, const float* __restrict__ emb,
    const ushort* __restrict__ M1t, const ushort* __restrict__ M2t,
    const float* __restrict__ mb1, const float* __restrict__ mb2,
    const float* __restrict__ ln_g, const float* __restrict__ ln_b,
    float* __restrict__ out, float* __restrict__ gsum, int N)
{
    __shared__ char lds[51200];
    const int tid = threadIdx.x;
    const int w = tid >> 6, l = tid & 63;
    const int li = l & 15, hi = l >> 4;
    const int base = blockIdx.x * 64;

    // stage M1t (32KB) + A-tile from aggh (16KB)
    for (int c = 0; c < 8; ++c) {
        int idx = c * 256 + tid;
        int col = idx >> 4, ch = idx & 15;
        uint4 v = *(const uint4*)(M1t + col * 128 + ch * 8);
        *(uint4*)(lds + col * 256 + ((ch * 16) ^ ((col & 7) << 4))) = v;
    }
    for (int c = 0; c < 4; ++c) {
        int idx = c * 256 + tid;
        int row = idx >> 4, ch = idx & 15;
        int gr = base + row; if (gr >= N) gr = N - 1;
        uint4 v = *(const uint4*)(aggh + (size_t)gr * 128 + ch * 8);
        *(uint4*)(lds + LDSA + row * 256 + ((ch * 16) ^ ((row & 7) << 4))) = v;
    }
    __syncthreads();

    // phase 1: K=128
    f32x4 C[8];
    #pragma unroll
    for (int ct = 0; ct < 8; ++ct) C[ct] = (f32x4){0.f, 0.f, 0.f, 0.f};
    {
        const int arow = w * 16 + li;
        const int asw = (arow & 7) << 4;
        #pragma unroll
        for (int ks = 0; ks < 4; ++ks) {
            short8 a = *(short8*)(lds + LDSA + arow * 256 + ((ks * 64 + hi * 16) ^ asw));
            #pragma unroll
            for (int ct = 0; ct < 8; ++ct) {
                int bcol = ct * 16 + li;
                short8 b = *(short8*)(lds + bcol * 256 + ((ks * 64 + hi * 16) ^ ((bcol & 7) << 4)));
                C[ct] = __builtin_amdgcn_mfma_f32_16x16x32_bf16(a, b, C[ct], 0, 0, 0);
            }
        }
    }
    __syncthreads();

    // H = relu(C+mb1) bf16 -> LDSA; stage M2t
    #pragma unroll
    for (int ct = 0; ct < 8; ++ct) {
        int col = ct * 16 + li;
        float bv = mb1[col];
        #pragma unroll
        for (int r = 0; r < 4; ++r) {
            int hrow = w * 16 + hi * 4 + r;
            float h = fmaxf(C[ct][r] + bv, 0.0f);
            *(ushort*)(lds + LDSA + hrow * 256 + ((col * 2) ^ ((hrow & 7) << 4))) = f2bf(h);
        }
    }
    for (int c = 0; c < 8; ++c) {
        int idx = c * 256 + tid;
        int col = idx >> 4, ch = idx & 15;
        uint4 v = *(const uint4*)(M2t + col * 128 + ch * 8);
        *(uint4*)(lds + col * 256 + ((ch * 16) ^ ((col & 7) << 4))) = v;
    }
    __syncthreads();

    // phase 2: K=128
    f32x4 C2[8];
    #pragma unroll
    for (int ct = 0; ct < 8; ++ct) C2[ct] = (f32x4){0.f, 0.f, 0.f, 0.f};
    {
        const int arow = w * 16 + li;
        const int asw = (arow & 7) << 4;
        #pragma unroll
        for (int ks = 0; ks < 4; ++ks) {
            short8 a = *(short8*)(lds + LDSA + arow * 256 + ((ks * 64 + hi * 16) ^ asw));
            #pragma unroll
            for (int ct = 0; ct < 8; ++ct) {
                int bcol = ct * 16 + li;
                short8 b = *(short8*)(lds + bcol * 256 + ((ks * 64 + hi * 16) ^ ((bcol & 7) << 4)));
                C2[ct] = __builtin_amdgcn_mfma_f32_16x16x32_bf16(a, b, C2[ct], 0, 0, 0);
            }
        }
    }

    // epilogue: y = C2 + mb2 + emb; LayerNorm per row; store; graph partials
    float y[8][4];
    #pragma unroll
    for (int ct = 0; ct < 8; ++ct) {
        int col = ct * 16 + li;
        float bv = mb2[col];
        #pragma unroll
        for (int r = 0; r < 4; ++r) {
            int gr = base + w * 16 + hi * 4 + r;
            int grc = gr < N ? gr : N - 1;
            y[ct][r] = C2[ct][r] + bv + emb[(size_t)grc * 128 + col];
        }
    }
    float rs[4] = {0, 0, 0, 0}, rq[4] = {0, 0, 0, 0};
    #pragma unroll
    for (int ct = 0; ct < 8; ++ct)
        #pragma unroll
        for (int r = 0; r < 4; ++r) { rs[r] += y[ct][r]; rq[r] += y[ct][r] * y[ct][r]; }
    #pragma unroll
    for (int m = 1; m < 16; m <<= 1) {
        #pragma unroll
        for (int r = 0; r < 4; ++r) {
            rs[r] += __shfl_xor(rs[r], m);
            rq[r] += __shfl_xor(rq[r], m);
        }
    }
    float mu[4], rstd[4];
    #pragma unroll
    for (int r = 0; r < 4; ++r) {
        mu[r] = rs[r] * (1.0f / HID);
        float var = rq[r] * (1.0f / HID) - mu[r] * mu[r];
        rstd[r] = rsqrtf(var + 1e-5f);
    }
    float cs[8];
    #pragma unroll
    for (int ct = 0; ct < 8; ++ct) {
        cs[ct] = 0.0f;
        int col = ct * 16 + li;
        float g = ln_g[col], bb = ln_b[col];
        #pragma unroll
        for (int r = 0; r < 4; ++r) {
            int gr = base + w * 16 + hi * 4 + r;
            float o = (y[ct][r] - mu[r]) * rstd[r] * g + bb;
            if (gr < N) {
                out[(size_t)gr * 128 + col] = o;
                cs[ct] += o;
            }
        }
    }
    #pragma unroll
    for (int m = 16; m < 64; m <<= 1) {
        #pragma unroll
        for (int ct = 0; ct < 8; ++ct) cs[ct] += __shfl_xor(cs[ct], m);
    }
    float* wsum = (float*)(lds + LDSS);
    if (hi == 0) {
        #pragma unroll
        for (int ct = 0; ct < 8; ++ct) wsum[w * 128 + ct * 16 + li] = cs[ct];
    }
    __syncthreads();
    if (tid < 128) {
        float s = wsum[tid] + wsum[128 + tid] + wsum[256 + tid] + wsum[384 + tid];
        atomicAdd(&gsum[tid], s);
    }
}

// ---------------------------------------------------------------------------
__global__ void k_graph(const float* __restrict__ gsum, float* __restrict__ out,
                        int N)
{
    int j = threadIdx.x;
    out[(size_t)N * HID + j] = gsum[j] * (1.0f / (float)N);
}

// ---------------------------------------------------------------------------
extern "C" void kernel_launch(void* const* d_in, const int* in_sizes, int n_in,
                              void* d_out, int out_size, void* d_ws, size_t ws_size,
                              hipStream_t stream)
{
    const float* feat      = (const float*)d_in[0];
    const int*   role_ids  = (const int*)  d_in[1];
    const int*   b2b_src   = (const int*)  d_in[2];
    const int*   b2b_dst   = (const int*)  d_in[3];
    const float* b2b_w     = (const float*)d_in[4];
    const int*   p2b_block = (const int*)  d_in[5];
    const float* p2b_w     = (const float*)d_in[6];
    const float* role_emb  = (const float*)d_in[7];
    const float* idx_emb   = (const float*)d_in[8];
    const float* W1        = (const float*)d_in[9];
    const float* b1        = (const float*)d_in[10];
    const float* W2        = (const float*)d_in[11];
    const float* b2        = (const float*)d_in[12];
    const float* M1        = (const float*)d_in[13];
    const float* mb1       = (const float*)d_in[14];
    const float* M2        = (const float*)d_in[15];
    const float* mb2       = (const float*)d_in[16];
    const float* ln_g      = (const float*)d_in[17];
    const float* ln_b      = (const float*)d_in[18];

    const int N = in_sizes[1];
    const int E = in_sizes[2];
    const int P = in_sizes[5];

    float* out = (float*)d_out;

    // workspace layout (16B aligned throughout)
    char* ws = (char*)d_ws;
    size_t embBytes  = (size_t)N * HID * sizeof(float);    // 51.2 MB
    size_t embhBytes = (size_t)N * HID * sizeof(ushort);   // 25.6 MB
    size_t entBytes  = (size_t)2 * E * sizeof(uint);       // 8 MB
    size_t vecBytes  = (size_t)N * sizeof(int);            // 400 KB

    const int B = (N + SCAN_C - 1) / SCAN_C;

    float*  emb     = (float*)ws;   ws += embBytes;
    ushort* embh    = (ushort*)ws;  ws += embhBytes;
    ushort* aggh    = (ushort*)ws;  ws += embhBytes;
    uint*   entries = (uint*)ws;    ws += entBytes;
    int*    startA  = (int*)ws;     ws += vecBytes;
    int*    cursor  = (int*)ws;     ws += vecBytes;
    int*    count   = (int*)ws;     ws += vecBytes;
    float*  pw      = (float*)ws;   ws += vecBytes;
    float*  gsum    = (float*)ws;   ws += 512;
    int*    bsum    = (int*)ws;     ws += 1024 * sizeof(int);
    int*    boff    = (int*)ws;     ws += 1024 * sizeof(int);
    ushort* W1t     = (ushort*)ws;  ws += 8192  * sizeof(ushort);
    ushort* W2t     = (ushort*)ws;  ws += 16384 * sizeof(ushort);
    ushort* M1t     = (ushort*)ws;  ws += 16384 * sizeof(ushort);
    ushort* M2t     = (ushort*)ws;  ws += 16384 * sizeof(ushort);

    // zero count | pw | gsum (contiguous)
    hipMemsetAsync(count, 0, 2 * vecBytes + 512, stream);

    const int nBlocks64 = (N + 63) / 64;

    k_prep<<<224, 256, 0, stream>>>(W1, W2, M1, M2, W1t, W2t, M1t, M2t);

    k_embed_mlp<<<nBlocks64, 256, 0, stream>>>(
        feat, role_ids, role_emb, idx_emb, W1t, b1, W2t, b2, emb, embh, N);

    k_count_pw<<<2048, 256, 0, stream>>>(b2b_src, b2b_dst, count,
                                         p2b_block, p2b_w, pw, E, P);

    k_scan1<<<B, 256, 0, stream>>>(count, bsum, N);
    k_scan2<<<1, 1024, 0, stream>>>(bsum, boff, B);
    k_scan3<<<B, 256, 0, stream>>>(count, boff, startA, cursor, N);

    k_scatter<<<2048, 256, 0, stream>>>(b2b_src, b2b_dst, b2b_w, cursor, entries, E);

    k_gather<<<(N + TILE - 1) / TILE, 256, 0, stream>>>(
        embh, emb, entries, startA, count, pw, aggh, N);

    k_msg_ln<<<nBlocks64, 256, 0, stream>>>(
        aggh, emb, M1t, M2t, mb1, mb2, ln_g, ln_b, out, gsum, N);

    k_graph<<<1, HID, 0, stream>>>(gsum, out, N);
}